// Round 1
// baseline (633.460 us; speedup 1.0000x reference)
//
#include <hip/hip_runtime.h>

#define DIN  256
#define DH   256
#define DOUT 128

// ---------------- degree count ----------------
__global__ __launch_bounds__(256)
void k_deg(const int* __restrict__ src, const int* __restrict__ dst,
           int* __restrict__ deg_f, int* __restrict__ deg_b, int E) {
    int e = blockIdx.x * 256 + threadIdx.x;
    if (e < E) {
        atomicAdd(&deg_f[dst[e]], 1);   // forward conv: segment by dst
        atomicAdd(&deg_b[src[e]], 1);   // backward conv: segment by src
    }
}

// ---------------- exclusive scan (1 block per direction) ----------------
__global__ __launch_bounds__(1024)
void k_scan(const int* __restrict__ deg_f, int* __restrict__ off_f, int* __restrict__ cur_f,
            const int* __restrict__ deg_b, int* __restrict__ off_b, int* __restrict__ cur_b,
            int n) {
    __shared__ int sm[1024];
    const int T = 1024;
    int t = threadIdx.x;
    const int* deg = blockIdx.x ? deg_b : deg_f;
    int* off = blockIdx.x ? off_b : off_f;
    int* cur = blockIdx.x ? cur_b : cur_f;

    int chunk = (n + T - 1) / T;
    int base = t * chunk;
    int sum = 0;
    for (int i = 0; i < chunk; ++i) {
        int idx = base + i;
        if (idx < n) sum += deg[idx];
    }
    sm[t] = sum;
    __syncthreads();
    // inclusive Hillis-Steele scan over thread partials
    for (int s = 1; s < T; s <<= 1) {
        int v = (t >= s) ? sm[t - s] : 0;
        __syncthreads();
        sm[t] += v;
        __syncthreads();
    }
    int run = sm[t] - sum;  // exclusive prefix of this thread's chunk
    for (int i = 0; i < chunk; ++i) {
        int idx = base + i;
        if (idx < n) {
            off[idx] = run;
            cur[idx] = run;
            run += deg[idx];
        }
    }
    if (t == T - 1) off[n] = sm[T - 1];
}

// ---------------- CSR fill ----------------
__global__ __launch_bounds__(256)
void k_fill(const int* __restrict__ src, const int* __restrict__ dst,
            int* __restrict__ cur_f, int* __restrict__ cur_b,
            int* __restrict__ lst_f, int* __restrict__ lst_b, int E) {
    int e = blockIdx.x * 256 + threadIdx.x;
    if (e < E) {
        int s = src[e], d = dst[e];
        int pf = atomicAdd(&cur_f[d], 1);
        lst_f[pf] = s;
        int pb = atomicAdd(&cur_b[s], 1);
        lst_b[pb] = d;
    }
}

// ---------------- dinv = rsqrt(deg + 1 self loop) ----------------
__global__ __launch_bounds__(256)
void k_dinv(const int* __restrict__ deg_f, const int* __restrict__ deg_b,
            float* __restrict__ dinv_f, float* __restrict__ dinv_b, int n) {
    int v = blockIdx.x * 256 + threadIdx.x;
    if (v < n) {
        dinv_f[v] = rsqrtf((float)(deg_f[v] + 1));
        dinv_b[v] = rsqrtf((float)(deg_b[v] + 1));
    }
}

// ---------------- f32 tiled GEMM: C[M,N] = A[M,K] @ W[K,N] ----------------
// BM=128, BN=64, BK=16, TM=8, TN=4, 256 threads.
// Epilogue: optional per-row scale (dinv), optional col bias, optional accumulate.
#define BM 128
#define BN 64
#define BK 16
__global__ __launch_bounds__(256)
void k_gemm(const float* __restrict__ A, const float* __restrict__ W,
            float* __restrict__ C, int M, int N, int K,
            const float* __restrict__ row_scale,
            const float* __restrict__ bias, int accumulate) {
    __shared__ float As[BK][BM + 4];   // transposed A tile, padded
    __shared__ float Ws[BK][BN];

    int tid = threadIdx.x;
    int bm = blockIdx.x * BM;
    int bn = blockIdx.y * BN;
    int tr = tid >> 4;          // 0..15
    int tc = tid & 15;          // 0..15
    int tm0 = tr * 8;
    int tn0 = tc * 4;

    float acc[8][4];
#pragma unroll
    for (int i = 0; i < 8; ++i)
#pragma unroll
        for (int j = 0; j < 4; ++j) acc[i][j] = 0.f;

    // A tile: 128x16 = 512 float4; thread handles f=tid and f=tid+256
    int ar = tid >> 2;              // 0..63
    int akk = (tid & 3) * 4;        // 0,4,8,12
    // W tile: 16x64 = 256 float4; thread f=tid
    int wkk = tid >> 4;             // 0..15
    int wnn = (tid & 15) * 4;       // 0..60

    for (int k0 = 0; k0 < K; k0 += BK) {
        {
            int r = ar;
            int row = bm + r;
            float4 v = make_float4(0.f, 0.f, 0.f, 0.f);
            if (row < M) v = *(const float4*)(A + (size_t)row * K + k0 + akk);
            As[akk + 0][r] = v.x; As[akk + 1][r] = v.y;
            As[akk + 2][r] = v.z; As[akk + 3][r] = v.w;

            r = ar + 64;
            row = bm + r;
            float4 v2 = make_float4(0.f, 0.f, 0.f, 0.f);
            if (row < M) v2 = *(const float4*)(A + (size_t)row * K + k0 + akk);
            As[akk + 0][r] = v2.x; As[akk + 1][r] = v2.y;
            As[akk + 2][r] = v2.z; As[akk + 3][r] = v2.w;
        }
        {
            float4 v = *(const float4*)(W + (size_t)(k0 + wkk) * N + bn + wnn);
            *(float4*)(&Ws[wkk][wnn]) = v;
        }
        __syncthreads();

#pragma unroll
        for (int k = 0; k < BK; ++k) {
            float a[8], w[4];
            *(float4*)&a[0] = *(const float4*)(&As[k][tm0]);
            *(float4*)&a[4] = *(const float4*)(&As[k][tm0 + 4]);
            *(float4*)&w[0] = *(const float4*)(&Ws[k][tn0]);
#pragma unroll
            for (int i = 0; i < 8; ++i)
#pragma unroll
                for (int j = 0; j < 4; ++j)
                    acc[i][j] = fmaf(a[i], w[j], acc[i][j]);
        }
        __syncthreads();
    }

    // epilogue
    float bb[4] = {0.f, 0.f, 0.f, 0.f};
    if (bias) {
        bb[0] = bias[bn + tn0 + 0]; bb[1] = bias[bn + tn0 + 1];
        bb[2] = bias[bn + tn0 + 2]; bb[3] = bias[bn + tn0 + 3];
    }
#pragma unroll
    for (int i = 0; i < 8; ++i) {
        int row = bm + tm0 + i;
        if (row < M) {
            float s = row_scale ? row_scale[row] : 1.0f;
            float* cp = C + (size_t)row * N + bn + tn0;
            float4 o;
            o.x = acc[i][0] * s + bb[0];
            o.y = acc[i][1] * s + bb[1];
            o.z = acc[i][2] * s + bb[2];
            o.w = acc[i][3] * s + bb[3];
            if (accumulate) {
                float4 old = *(const float4*)cp;
                o.x += old.x; o.y += old.y; o.z += old.z; o.w += old.w;
            }
            *(float4*)cp = o;
        }
    }
}

// ---------------- CSR aggregation: out[v] = dinv[v]*(sum g[u] + g[v]) + b ----------------
// 4 waves/block, one wave per node; 64 lanes x float4 = 256 features.
__global__ __launch_bounds__(256)
void k_aggregate(const float* __restrict__ g,
                 const int* __restrict__ off, const int* __restrict__ lst,
                 const float* __restrict__ dinv, const float* __restrict__ bias,
                 float* __restrict__ out, int n, int relu) {
    int wave = threadIdx.x >> 6;
    int lane = threadIdx.x & 63;
    int v = blockIdx.x * 4 + wave;
    if (v >= n) return;
    int c4 = lane * 4;

    float4 acc = *(const float4*)(g + (size_t)v * DH + c4);  // self loop
    int s0 = off[v], s1 = off[v + 1];
    for (int j = s0; j < s1; ++j) {
        int u = lst[j];
        float4 m = *(const float4*)(g + (size_t)u * DH + c4);
        acc.x += m.x; acc.y += m.y; acc.z += m.z; acc.w += m.w;
    }
    float sc = dinv[v];
    float4 b4 = *(const float4*)(bias + c4);
    float4 o;
    o.x = acc.x * sc + b4.x;
    o.y = acc.y * sc + b4.y;
    o.z = acc.z * sc + b4.z;
    o.w = acc.w * sc + b4.w;
    if (relu) {
        o.x = fmaxf(o.x, 0.f); o.y = fmaxf(o.y, 0.f);
        o.z = fmaxf(o.z, 0.f); o.w = fmaxf(o.w, 0.f);
    }
    *(float4*)(out + (size_t)v * DH + c4) = o;
}

extern "C" void kernel_launch(void* const* d_in, const int* in_sizes, int n_in,
                              void* d_out, int out_size, void* d_ws, size_t ws_size,
                              hipStream_t stream) {
    const float* x    = (const float*)d_in[0];
    const int*   ei   = (const int*)d_in[1];
    const float* Wf1  = (const float*)d_in[2];
    const float* bf1  = (const float*)d_in[3];
    const float* Wf2  = (const float*)d_in[4];
    const float* bf2  = (const float*)d_in[5];
    const float* Wb1  = (const float*)d_in[6];
    const float* bb1  = (const float*)d_in[7];
    const float* Wb2  = (const float*)d_in[8];
    const float* bb2  = (const float*)d_in[9];
    const float* Wfin = (const float*)d_in[10];
    const float* bfin = (const float*)d_in[11];
    float* out = (float*)d_out;

    const int n = in_sizes[0] / DIN;   // 20000
    const int E = in_sizes[1] / 2;     // 320000
    const int* src = ei;
    const int* dst = ei + E;

    char* p = (char*)d_ws;
    auto take = [&](size_t bytes) -> void* {
        void* q = (void*)p;
        p += (bytes + 255) & ~(size_t)255;
        return q;
    };
    float* tmpA   = (float*)take((size_t)n * DH * sizeof(float));
    float* tmpB   = (float*)take((size_t)n * DH * sizeof(float));
    int*   deg_f  = (int*)take((size_t)n * sizeof(int));
    int*   deg_b  = (int*)take((size_t)n * sizeof(int));
    int*   off_f  = (int*)take((size_t)(n + 1) * sizeof(int));
    int*   off_b  = (int*)take((size_t)(n + 1) * sizeof(int));
    int*   cur_f  = (int*)take((size_t)n * sizeof(int));
    int*   cur_b  = (int*)take((size_t)n * sizeof(int));
    int*   lst_f  = (int*)take((size_t)E * sizeof(int));
    int*   lst_b  = (int*)take((size_t)E * sizeof(int));
    float* dinv_f = (float*)take((size_t)n * sizeof(float));
    float* dinv_b = (float*)take((size_t)n * sizeof(float));

    hipMemsetAsync(deg_f, 0, (size_t)n * sizeof(int), stream);
    hipMemsetAsync(deg_b, 0, (size_t)n * sizeof(int), stream);

    int eb = (E + 255) / 256;
    k_deg<<<eb, 256, 0, stream>>>(src, dst, deg_f, deg_b, E);
    k_scan<<<2, 1024, 0, stream>>>(deg_f, off_f, cur_f, deg_b, off_b, cur_b, n);
    k_fill<<<eb, 256, 0, stream>>>(src, dst, cur_f, cur_b, lst_f, lst_b, E);
    k_dinv<<<(n + 255) / 256, 256, 0, stream>>>(deg_f, deg_b, dinv_f, dinv_b, n);

    dim3 g256((n + BM - 1) / BM, DH / BN);
    dim3 g128((n + BM - 1) / BM, DOUT / BN);
    int ab = (n + 3) / 4;

    // ---- forward stack ----
    k_gemm<<<g256, 256, 0, stream>>>(x,    Wf1, tmpA, n, DH, DIN, dinv_f, nullptr, 0);
    k_aggregate<<<ab, 256, 0, stream>>>(tmpA, off_f, lst_f, dinv_f, bf1, tmpB, n, 1);
    k_gemm<<<g256, 256, 0, stream>>>(tmpB, Wf2, tmpA, n, DH, DH, dinv_f, nullptr, 0);
    k_aggregate<<<ab, 256, 0, stream>>>(tmpA, off_f, lst_f, dinv_f, bf2, tmpB, n, 0);
    // out = x_fwd @ Wfin[0:256,:] + bfin
    k_gemm<<<g128, 256, 0, stream>>>(tmpB, Wfin, out, n, DOUT, DH, nullptr, bfin, 0);

    // ---- backward stack (edges reversed) ----
    k_gemm<<<g256, 256, 0, stream>>>(x,    Wb1, tmpA, n, DH, DIN, dinv_b, nullptr, 0);
    k_aggregate<<<ab, 256, 0, stream>>>(tmpA, off_b, lst_b, dinv_b, bb1, tmpB, n, 1);
    k_gemm<<<g256, 256, 0, stream>>>(tmpB, Wb2, tmpA, n, DH, DH, dinv_b, nullptr, 0);
    k_aggregate<<<ab, 256, 0, stream>>>(tmpA, off_b, lst_b, dinv_b, bb2, tmpB, n, 0);
    // out += x_bwd @ Wfin[256:512,:]
    k_gemm<<<g128, 256, 0, stream>>>(tmpB, Wfin + (size_t)DH * DOUT, out, n, DOUT, DH, nullptr, nullptr, 1);
}

// Round 2
// 497.328 us; speedup vs baseline: 1.2737x; 1.2737x over previous
//
#include <hip/hip_runtime.h>

typedef unsigned int   u32;
typedef unsigned short u16;
typedef __attribute__((ext_vector_type(8))) short bf16x8;
typedef __attribute__((ext_vector_type(4))) float f32x4;

#define DH   256
#define DOUT 128

// ---------- bf16 helpers (RNE) ----------
__device__ __forceinline__ u16 f2bf(float f) {
    u32 u = __float_as_uint(f);
    u32 r = u + 0x7fffu + ((u >> 16) & 1u);
    return (u16)(r >> 16);
}
__device__ __forceinline__ float bf2f(u16 h) {
    return __uint_as_float(((u32)h) << 16);
}
__device__ __forceinline__ void gl_lds16(const void* g, void* l) {
    __builtin_amdgcn_global_load_lds(
        (const __attribute__((address_space(1))) u32*)g,
        (__attribute__((address_space(3))) u32*)l, 16, 0, 0);
}
__device__ __forceinline__ void st16(void* dst, const u16* h) {
    uint4 q;
    q.x = (u32)h[0] | ((u32)h[1] << 16);
    q.y = (u32)h[2] | ((u32)h[3] << 16);
    q.z = (u32)h[4] | ((u32)h[5] << 16);
    q.w = (u32)h[6] | ((u32)h[7] << 16);
    *(uint4*)dst = q;
}

// ---------------- degree count ----------------
__global__ __launch_bounds__(256)
void k_deg(const int* __restrict__ src, const int* __restrict__ dst,
           int* __restrict__ deg_f, int* __restrict__ deg_b, int E) {
    int e = blockIdx.x * 256 + threadIdx.x;
    if (e < E) {
        atomicAdd(&deg_f[dst[e]], 1);
        atomicAdd(&deg_b[src[e]], 1);
    }
}

// ---------------- exclusive scan (1 block per direction) ----------------
__global__ __launch_bounds__(1024)
void k_scan(const int* __restrict__ deg_f, int* __restrict__ off_f, int* __restrict__ cur_f,
            const int* __restrict__ deg_b, int* __restrict__ off_b, int* __restrict__ cur_b,
            int n) {
    __shared__ int sm[1024];
    const int T = 1024;
    int t = threadIdx.x;
    const int* deg = blockIdx.x ? deg_b : deg_f;
    int* off = blockIdx.x ? off_b : off_f;
    int* cur = blockIdx.x ? cur_b : cur_f;

    int chunk = (n + T - 1) / T;
    int base = t * chunk;
    int sum = 0;
    for (int i = 0; i < chunk; ++i) {
        int idx = base + i;
        if (idx < n) sum += deg[idx];
    }
    sm[t] = sum;
    __syncthreads();
    for (int s = 1; s < T; s <<= 1) {
        int v = (t >= s) ? sm[t - s] : 0;
        __syncthreads();
        sm[t] += v;
        __syncthreads();
    }
    int run = sm[t] - sum;
    for (int i = 0; i < chunk; ++i) {
        int idx = base + i;
        if (idx < n) {
            off[idx] = run;
            cur[idx] = run;
            run += deg[idx];
        }
    }
    if (t == T - 1) off[n] = sm[T - 1];
}

// ---------------- CSR fill ----------------
__global__ __launch_bounds__(256)
void k_fill(const int* __restrict__ src, const int* __restrict__ dst,
            int* __restrict__ cur_f, int* __restrict__ cur_b,
            int* __restrict__ lst_f, int* __restrict__ lst_b, int E) {
    int e = blockIdx.x * 256 + threadIdx.x;
    if (e < E) {
        int s = src[e], d = dst[e];
        int pf = atomicAdd(&cur_f[d], 1);
        lst_f[pf] = s;
        int pb = atomicAdd(&cur_b[s], 1);
        lst_b[pb] = d;
    }
}

// ---------------- dinv ----------------
__global__ __launch_bounds__(256)
void k_dinv(const int* __restrict__ deg_f, const int* __restrict__ deg_b,
            float* __restrict__ dinv_f, float* __restrict__ dinv_b, int n) {
    int v = blockIdx.x * 256 + threadIdx.x;
    if (v < n) {
        dinv_f[v] = rsqrtf((float)(deg_f[v] + 1));
        dinv_b[v] = rsqrtf((float)(deg_b[v] + 1));
    }
}

// ---------------- weight transpose + hi/lo split: Wt[N][K] from W[K][N] ----------------
__global__ __launch_bounds__(256)
void k_wsplit(const float* __restrict__ W, u16* __restrict__ thi, u16* __restrict__ tlo,
              int K, int N) {
    int idx = blockIdx.x * 256 + threadIdx.x;
    if (idx >= K * N) return;
    int ni = idx / K, ki = idx - ni * K;
    float v = W[(size_t)ki * N + ni];
    u16 h = f2bf(v);
    thi[idx] = h;
    tlo[idx] = f2bf(v - bf2f(h));
}

// ---------------- MFMA GEMM: C[M,N] = A[M,256] @ Bt[N,256]^T ----------------
// Tile 128x128, BK=32, 256 threads = 4 waves (2x2), wave computes 64x64.
// A via split bf16 (hi+lo), 3 MFMA passes: hi*hi + hi*lo + lo*hi.
// AMODE 0: A given as bf16 hi/lo planes [M][256] (gload_lds staging)
// AMODE 1: A given as f32 [M][256] (reg-stage + convert)
// EMODE 0: C = rowscale[row] * acc  -> bf16 hi/lo planes
// EMODE 1: C = acc + bias[col] (+ C old if accumulate) -> f32
template<int AMODE, int EMODE>
__global__ __launch_bounds__(256)
void k_gemm_mfma(const void* __restrict__ Aptr, const u16* __restrict__ Alo,
                 const u16* __restrict__ Bhi, const u16* __restrict__ Blo, int ldb,
                 float* __restrict__ Cf, u16* __restrict__ Chi, u16* __restrict__ Clo,
                 const float* __restrict__ rowscale, const float* __restrict__ bias,
                 int M, int N, int accumulate)
{
    __shared__ char smem[32768];   // Ahi@0  Alo@8192  Bhi@16384  Blo@24576

    const int tid  = threadIdx.x;
    const int lane = tid & 63;
    const int wid  = tid >> 6;
    const int wm   = wid >> 1, wn = wid & 1;
    const int bm   = blockIdx.x * 128;
    const int bn   = blockIdx.y * 128;

    f32x4 acc[4][4];
#pragma unroll
    for (int i = 0; i < 4; ++i)
#pragma unroll
        for (int j = 0; j < 4; ++j) acc[i][j] = (f32x4){0.f, 0.f, 0.f, 0.f};

    // staging swizzle: LDS granule (row,g) holds global granule g ^ swz(row),
    // swz(r) = (r&3)^((r>>2)&3). For the stage pattern both terms are lane-derived:
    const int gsw  = ((lane >> 2) & 3) ^ ((lane >> 4) & 3);
    const int gsta = ((lane & 3) ^ gsw) << 4;      // source granule byte offset
    // frag-read swizzle
    const int sl   = (lane & 3) ^ ((lane >> 2) & 3);
    const int hi4  = lane >> 4;
    const int gsel = ((hi4 ^ sl) << 4);
    const int frow = lane & 15;

    for (int k0 = 0; k0 < 256; k0 += 32) {
        if (k0) __syncthreads();

        // ---- stage B (bf16 planes, ldb bytes per row) ----
#pragma unroll
        for (int p = 0; p < 2; ++p) {
            int c   = p * 4 + wid;
            int row = c * 16 + (lane >> 2);          // 0..127
            size_t rb = (size_t)(bn + row) * ldb + (size_t)k0 * 2 + gsta;
            gl_lds16((const char*)Bhi + rb, smem + 16384 + c * 1024);
            gl_lds16((const char*)Blo + rb, smem + 24576 + c * 1024);
        }
        // ---- stage A ----
        if (AMODE == 0) {
            const u16* Ah = (const u16*)Aptr;
#pragma unroll
            for (int p = 0; p < 2; ++p) {
                int c   = p * 4 + wid;
                int row = c * 16 + (lane >> 2);
                int grow = bm + row; if (grow >= M) grow = M - 1;
                size_t rb = (size_t)grow * 512 + (size_t)k0 * 2 + gsta;
                gl_lds16((const char*)Ah  + rb, smem + c * 1024);
                gl_lds16((const char*)Alo + rb, smem + 8192 + c * 1024);
            }
        } else {
            const float* Af = (const float*)Aptr;
            int row  = tid >> 1;
            int half = tid & 1;
            int grow = bm + row; if (grow >= M) grow = M - 1;
            const float* srcp = Af + (size_t)grow * 256 + k0 + half * 16;
            float vv[16];
            *(float4*)(vv + 0)  = *(const float4*)(srcp + 0);
            *(float4*)(vv + 4)  = *(const float4*)(srcp + 4);
            *(float4*)(vv + 8)  = *(const float4*)(srcp + 8);
            *(float4*)(vv + 12) = *(const float4*)(srcp + 12);
            u16 h[16], l[16];
#pragma unroll
            for (int i = 0; i < 16; ++i) {
                h[i] = f2bf(vv[i]);
                l[i] = f2bf(vv[i] - bf2f(h[i]));
            }
            int swz = (row & 3) ^ ((row >> 2) & 3);
            char* dh = smem + row * 64;
            char* dl = smem + 8192 + row * 64;
            st16(dh + (((half * 2 + 0) ^ swz) << 4), h + 0);
            st16(dh + (((half * 2 + 1) ^ swz) << 4), h + 8);
            st16(dl + (((half * 2 + 0) ^ swz) << 4), l + 0);
            st16(dl + (((half * 2 + 1) ^ swz) << 4), l + 8);
        }
        __syncthreads();

        // ---- fragments ----
        bf16x8 ah[4], al[4], bh[4], bl[4];
#pragma unroll
        for (int fm = 0; fm < 4; ++fm) {
            int r = wm * 64 + fm * 16 + frow;
            ah[fm] = *(const bf16x8*)(smem + r * 64 + gsel);
            al[fm] = *(const bf16x8*)(smem + 8192 + r * 64 + gsel);
        }
#pragma unroll
        for (int fn = 0; fn < 4; ++fn) {
            int r = wn * 64 + fn * 16 + frow;
            bh[fn] = *(const bf16x8*)(smem + 16384 + r * 64 + gsel);
            bl[fn] = *(const bf16x8*)(smem + 24576 + r * 64 + gsel);
        }
        // ---- 3-pass MFMA ----
#pragma unroll
        for (int fm = 0; fm < 4; ++fm)
#pragma unroll
            for (int fn = 0; fn < 4; ++fn)
                acc[fm][fn] = __builtin_amdgcn_mfma_f32_16x16x32_bf16(ah[fm], bh[fn], acc[fm][fn], 0, 0, 0);
#pragma unroll
        for (int fm = 0; fm < 4; ++fm)
#pragma unroll
            for (int fn = 0; fn < 4; ++fn)
                acc[fm][fn] = __builtin_amdgcn_mfma_f32_16x16x32_bf16(ah[fm], bl[fn], acc[fm][fn], 0, 0, 0);
#pragma unroll
        for (int fm = 0; fm < 4; ++fm)
#pragma unroll
            for (int fn = 0; fn < 4; ++fn)
                acc[fm][fn] = __builtin_amdgcn_mfma_f32_16x16x32_bf16(al[fm], bh[fn], acc[fm][fn], 0, 0, 0);
    }

    // ---- epilogue ----
    if (EMODE == 0) {
#pragma unroll
        for (int fm = 0; fm < 4; ++fm) {
#pragma unroll
            for (int q = 0; q < 4; ++q) {
                int row = bm + wm * 64 + fm * 16 + hi4 * 4 + q;
                if (row < M) {
                    float s = rowscale[row];
#pragma unroll
                    for (int fn = 0; fn < 4; ++fn) {
                        int col = bn + wn * 64 + fn * 16 + frow;
                        float v = acc[fm][fn][q] * s;
                        u16 hb = f2bf(v);
                        Chi[(size_t)row * N + col] = hb;
                        Clo[(size_t)row * N + col] = f2bf(v - bf2f(hb));
                    }
                }
            }
        }
    } else {
#pragma unroll
        for (int fm = 0; fm < 4; ++fm) {
#pragma unroll
            for (int q = 0; q < 4; ++q) {
                int row = bm + wm * 64 + fm * 16 + hi4 * 4 + q;
                if (row < M) {
#pragma unroll
                    for (int fn = 0; fn < 4; ++fn) {
                        int col = bn + wn * 64 + fn * 16 + frow;
                        float v = acc[fm][fn][q];
                        if (bias) v += bias[col];
                        float* cp = Cf + (size_t)row * N + col;
                        if (accumulate) v += *cp;
                        *cp = v;
                    }
                }
            }
        }
    }
}

// ---------------- CSR aggregation over bf16-hi plane ----------------
// out[v] = dinv[v]*( sum_{u in N(v)} ghi[u] + (ghi[v]+glo[v]) ) + b   (split to hi/lo)
__global__ __launch_bounds__(256)
void k_agg(const u16* __restrict__ ghi, const u16* __restrict__ glo,
           const int* __restrict__ off, const int* __restrict__ lst,
           const float* __restrict__ dinv, const float* __restrict__ bias,
           u16* __restrict__ ohi, u16* __restrict__ olo, int n, int relu)
{
    int wv = threadIdx.x >> 6, lane = threadIdx.x & 63;
    int v = blockIdx.x * 4 + wv;
    if (v >= n) return;
    int c4 = lane * 4;

    ushort4 sh = *(const ushort4*)(ghi + (size_t)v * 256 + c4);
    ushort4 sl = *(const ushort4*)(glo + (size_t)v * 256 + c4);
    float a0 = bf2f(sh.x) + bf2f(sl.x);
    float a1 = bf2f(sh.y) + bf2f(sl.y);
    float a2 = bf2f(sh.z) + bf2f(sl.z);
    float a3 = bf2f(sh.w) + bf2f(sl.w);

    int s0 = off[v], s1 = off[v + 1];
    for (int j = s0; j < s1; ++j) {
        int u = lst[j];
        ushort4 m = *(const ushort4*)(ghi + (size_t)u * 256 + c4);
        a0 += bf2f(m.x); a1 += bf2f(m.y); a2 += bf2f(m.z); a3 += bf2f(m.w);
    }
    float sc = dinv[v];
    float4 b4 = *(const float4*)(bias + c4);
    float o0 = a0 * sc + b4.x;
    float o1 = a1 * sc + b4.y;
    float o2 = a2 * sc + b4.z;
    float o3 = a3 * sc + b4.w;
    if (relu) {
        o0 = fmaxf(o0, 0.f); o1 = fmaxf(o1, 0.f);
        o2 = fmaxf(o2, 0.f); o3 = fmaxf(o3, 0.f);
    }
    ushort4 rh, rl;
    rh.x = f2bf(o0); rl.x = f2bf(o0 - bf2f(rh.x));
    rh.y = f2bf(o1); rl.y = f2bf(o1 - bf2f(rh.y));
    rh.z = f2bf(o2); rl.z = f2bf(o2 - bf2f(rh.z));
    rh.w = f2bf(o3); rl.w = f2bf(o3 - bf2f(rh.w));
    *(ushort4*)(ohi + (size_t)v * 256 + c4) = rh;
    *(ushort4*)(olo + (size_t)v * 256 + c4) = rl;
}

extern "C" void kernel_launch(void* const* d_in, const int* in_sizes, int n_in,
                              void* d_out, int out_size, void* d_ws, size_t ws_size,
                              hipStream_t stream) {
    const float* x    = (const float*)d_in[0];
    const int*   ei   = (const int*)d_in[1];
    const float* Wf1  = (const float*)d_in[2];
    const float* bf1  = (const float*)d_in[3];
    const float* Wf2  = (const float*)d_in[4];
    const float* bf2  = (const float*)d_in[5];
    const float* Wb1  = (const float*)d_in[6];
    const float* bb1  = (const float*)d_in[7];
    const float* Wb2  = (const float*)d_in[8];
    const float* bb2  = (const float*)d_in[9];
    const float* Wfin = (const float*)d_in[10];
    const float* bfin = (const float*)d_in[11];
    float* out = (float*)d_out;

    const int n = in_sizes[0] / 256;   // 20000
    const int E = in_sizes[1] / 2;     // 320000
    const int* src = ei;
    const int* dst = ei + E;

    char* p = (char*)d_ws;
    auto take = [&](size_t bytes) -> void* {
        void* q = (void*)p;
        p += (bytes + 255) & ~(size_t)255;
        return q;
    };
    u16* P1h = (u16*)take((size_t)n * 256 * 2);
    u16* P1l = (u16*)take((size_t)n * 256 * 2);
    u16* P2h = (u16*)take((size_t)n * 256 * 2);
    u16* P2l = (u16*)take((size_t)n * 256 * 2);
    u16* w1f_h = (u16*)take(65536 * 2); u16* w1f_l = (u16*)take(65536 * 2);
    u16* w2f_h = (u16*)take(65536 * 2); u16* w2f_l = (u16*)take(65536 * 2);
    u16* w1b_h = (u16*)take(65536 * 2); u16* w1b_l = (u16*)take(65536 * 2);
    u16* w2b_h = (u16*)take(65536 * 2); u16* w2b_l = (u16*)take(65536 * 2);
    u16* wfin_h = (u16*)take(65536 * 2); u16* wfin_l = (u16*)take(65536 * 2);
    int*   deg_f  = (int*)take((size_t)n * sizeof(int));
    int*   deg_b  = (int*)take((size_t)n * sizeof(int));
    int*   off_f  = (int*)take((size_t)(n + 1) * sizeof(int));
    int*   off_b  = (int*)take((size_t)(n + 1) * sizeof(int));
    int*   cur_f  = (int*)take((size_t)n * sizeof(int));
    int*   cur_b  = (int*)take((size_t)n * sizeof(int));
    int*   lst_f  = (int*)take((size_t)E * sizeof(int));
    int*   lst_b  = (int*)take((size_t)E * sizeof(int));
    float* dinv_f = (float*)take((size_t)n * sizeof(float));
    float* dinv_b = (float*)take((size_t)n * sizeof(float));

    hipMemsetAsync(deg_f, 0, (size_t)n * sizeof(int), stream);
    hipMemsetAsync(deg_b, 0, (size_t)n * sizeof(int), stream);

    int eb = (E + 255) / 256;
    k_deg<<<eb, 256, 0, stream>>>(src, dst, deg_f, deg_b, E);
    k_scan<<<2, 1024, 0, stream>>>(deg_f, off_f, cur_f, deg_b, off_b, cur_b, n);
    k_fill<<<eb, 256, 0, stream>>>(src, dst, cur_f, cur_b, lst_f, lst_b, E);
    k_dinv<<<(n + 255) / 256, 256, 0, stream>>>(deg_f, deg_b, dinv_f, dinv_b, n);

    int wb = (65536 + 255) / 256;
    k_wsplit<<<wb, 256, 0, stream>>>(Wf1,  w1f_h, w1f_l, 256, 256);
    k_wsplit<<<wb, 256, 0, stream>>>(Wf2,  w2f_h, w2f_l, 256, 256);
    k_wsplit<<<wb, 256, 0, stream>>>(Wb1,  w1b_h, w1b_l, 256, 256);
    k_wsplit<<<wb, 256, 0, stream>>>(Wb2,  w2b_h, w2b_l, 256, 256);
    k_wsplit<<<wb, 256, 0, stream>>>(Wfin, wfin_h, wfin_l, 512, 128);

    dim3 gBig((n + 127) / 128, 2);    // N=256
    dim3 gFin((n + 127) / 128, 1);    // N=128
    int ab = (n + 3) / 4;

    // ---- forward stack ----
    k_gemm_mfma<1, 0><<<gBig, 256, 0, stream>>>(x, nullptr, w1f_h, w1f_l, 512,
        nullptr, P1h, P1l, dinv_f, nullptr, n, 256, 0);
    k_agg<<<ab, 256, 0, stream>>>(P1h, P1l, off_f, lst_f, dinv_f, bf1, P2h, P2l, n, 1);
    k_gemm_mfma<0, 0><<<gBig, 256, 0, stream>>>(P2h, P2l, w2f_h, w2f_l, 512,
        nullptr, P1h, P1l, dinv_f, nullptr, n, 256, 0);
    k_agg<<<ab, 256, 0, stream>>>(P1h, P1l, off_f, lst_f, dinv_f, bf2, P2h, P2l, n, 0);
    k_gemm_mfma<0, 1><<<gFin, 256, 0, stream>>>(P2h, P2l, wfin_h, wfin_l, 1024,
        out, nullptr, nullptr, nullptr, bfin, n, 128, 0);

    // ---- backward stack ----
    k_gemm_mfma<1, 0><<<gBig, 256, 0, stream>>>(x, nullptr, w1b_h, w1b_l, 512,
        nullptr, P1h, P1l, dinv_b, nullptr, n, 256, 0);
    k_agg<<<ab, 256, 0, stream>>>(P1h, P1l, off_b, lst_b, dinv_b, bb1, P2h, P2l, n, 1);
    k_gemm_mfma<0, 0><<<gBig, 256, 0, stream>>>(P2h, P2l, w2b_h, w2b_l, 512,
        nullptr, P1h, P1l, dinv_b, nullptr, n, 256, 0);
    k_agg<<<ab, 256, 0, stream>>>(P1h, P1l, off_b, lst_b, dinv_b, bb2, P2h, P2l, n, 0);
    k_gemm_mfma<0, 1><<<gFin, 256, 0, stream>>>(P2h, P2l, wfin_h + 256, wfin_l + 256, 1024,
        out, nullptr, nullptr, nullptr, nullptr, n, 128, 1);
}

// Round 4
// 365.292 us; speedup vs baseline: 1.7341x; 1.3615x over previous
//
#include <hip/hip_runtime.h>

typedef unsigned int   u32;
typedef unsigned short u16;
typedef __attribute__((ext_vector_type(8))) short bf16x8;
typedef __attribute__((ext_vector_type(4))) float f32x4;

// ---------- bf16 helpers (RNE) ----------
__device__ __forceinline__ u16 f2bf(float f) {
    u32 u = __float_as_uint(f);
    u32 r = u + 0x7fffu + ((u >> 16) & 1u);
    return (u16)(r >> 16);
}
__device__ __forceinline__ float bf2f(u16 h) {
    return __uint_as_float(((u32)h) << 16);
}
__device__ __forceinline__ void gl_lds16(const void* g, void* l) {
    __builtin_amdgcn_global_load_lds(
        (const __attribute__((address_space(1))) u32*)g,
        (__attribute__((address_space(3))) u32*)l, 16, 0, 0);
}
__device__ __forceinline__ void st16(void* dst, const u16* h) {
    uint4 q;
    q.x = (u32)h[0] | ((u32)h[1] << 16);
    q.y = (u32)h[2] | ((u32)h[3] << 16);
    q.z = (u32)h[4] | ((u32)h[5] << 16);
    q.w = (u32)h[6] | ((u32)h[7] << 16);
    *(uint4*)dst = q;
}

// ---------------- degree count ----------------
__global__ __launch_bounds__(256)
void k_deg(const int* __restrict__ src, const int* __restrict__ dst,
           int* __restrict__ deg_f, int* __restrict__ deg_b, int E) {
    int e = blockIdx.x * 256 + threadIdx.x;
    if (e < E) {
        atomicAdd(&deg_f[dst[e]], 1);
        atomicAdd(&deg_b[src[e]], 1);
    }
}

// ---------------- exclusive scan (1 block per direction) ----------------
__global__ __launch_bounds__(1024)
void k_scan(const int* __restrict__ deg_f, int* __restrict__ off_f, int* __restrict__ cur_f,
            const int* __restrict__ deg_b, int* __restrict__ off_b, int* __restrict__ cur_b,
            int n) {
    __shared__ int sm[1024];
    const int T = 1024;
    int t = threadIdx.x;
    const int* deg = blockIdx.x ? deg_b : deg_f;
    int* off = blockIdx.x ? off_b : off_f;
    int* cur = blockIdx.x ? cur_b : cur_f;

    int chunk = (n + T - 1) / T;
    int base = t * chunk;
    int sum = 0;
    for (int i = 0; i < chunk; ++i) {
        int idx = base + i;
        if (idx < n) sum += deg[idx];
    }
    sm[t] = sum;
    __syncthreads();
    for (int s = 1; s < T; s <<= 1) {
        int v = (t >= s) ? sm[t - s] : 0;
        __syncthreads();
        sm[t] += v;
        __syncthreads();
    }
    int run = sm[t] - sum;
    for (int i = 0; i < chunk; ++i) {
        int idx = base + i;
        if (idx < n) {
            off[idx] = run;
            cur[idx] = run;
            run += deg[idx];
        }
    }
    if (t == T - 1) off[n] = sm[T - 1];
}

// ---------------- CSR fill ----------------
__global__ __launch_bounds__(256)
void k_fill(const int* __restrict__ src, const int* __restrict__ dst,
            int* __restrict__ cur_f, int* __restrict__ cur_b,
            int* __restrict__ lst_f, int* __restrict__ lst_b, int E) {
    int e = blockIdx.x * 256 + threadIdx.x;
    if (e < E) {
        int s = src[e], d = dst[e];
        int pf = atomicAdd(&cur_f[d], 1);
        lst_f[pf] = s;
        int pb = atomicAdd(&cur_b[s], 1);
        lst_b[pb] = d;
    }
}

// ---------------- dinv ----------------
__global__ __launch_bounds__(256)
void k_dinv(const int* __restrict__ deg_f, const int* __restrict__ deg_b,
            float* __restrict__ dinv_f, float* __restrict__ dinv_b, int n) {
    int v = blockIdx.x * 256 + threadIdx.x;
    if (v < n) {
        dinv_f[v] = rsqrtf((float)(deg_f[v] + 1));
        dinv_b[v] = rsqrtf((float)(deg_b[v] + 1));
    }
}

// ---------------- weight transpose + hi/lo split: Wt[N][K] from W[K][N] ----------------
__global__ __launch_bounds__(256)
void k_wsplit(const float* __restrict__ W, u16* __restrict__ thi, u16* __restrict__ tlo,
              int K, int N) {
    int idx = blockIdx.x * 256 + threadIdx.x;
    if (idx >= K * N) return;
    int ni = idx / K, ki = idx - ni * K;
    float v = W[(size_t)ki * N + ni];
    u16 h = f2bf(v);
    thi[idx] = h;
    tlo[idx] = f2bf(v - bf2f(h));
}

// ---------------- cvec = bfin + bf2^T Wfin[0:256] + bb2^T Wfin[256:512] ----------------
__global__ __launch_bounds__(128)
void k_cvec(const float* __restrict__ bfin, const float* __restrict__ bf2,
            const float* __restrict__ bb2, const float* __restrict__ Wfin,
            float* __restrict__ cvec) {
    int j = threadIdx.x;   // 0..127
    float s = bfin[j];
    for (int k = 0; k < 256; ++k) {
        s += bf2[k] * Wfin[(size_t)k * 128 + j];
        s += bb2[k] * Wfin[(size_t)(256 + k) * 128 + j];
    }
    cvec[j] = s;
}

// ---------------- MFMA GEMM (fwd+bwd merged via blockIdx.z) ----------------
// C[M,N] = A[M,256] @ Bt[N,256]^T ; tile 128x128, BK=32, 4 waves (2x2).
// A via split bf16 (hi+lo), 3 MFMA passes. Output: bf16 hi/lo planes,
// optional per-row scale (null -> 1).
// AMODE 0: A = bf16 hi/lo planes [M][256];  AMODE 1: A = f32 [M][256].
template<int AMODE>
__global__ __launch_bounds__(256)
void k_gemm2(const void* __restrict__ A0, const void* __restrict__ A1,
             const u16* __restrict__ Alo0, const u16* __restrict__ Alo1,
             const u16* __restrict__ Bhi0, const u16* __restrict__ Blo0,
             const u16* __restrict__ Bhi1, const u16* __restrict__ Blo1, int ldb,
             u16* __restrict__ Chi0, u16* __restrict__ Clo0,
             u16* __restrict__ Chi1, u16* __restrict__ Clo1,
             const float* __restrict__ rs0, const float* __restrict__ rs1,
             int M, int N)
{
    __shared__ char smem[32768];   // Ahi@0  Alo@8192  Bhi@16384  Blo@24576

    const int z = blockIdx.z;
    const void* Aptr = z ? A1 : A0;
    const u16* Alo   = z ? Alo1 : Alo0;
    const u16* Bhi   = z ? Bhi1 : Bhi0;
    const u16* Blo   = z ? Blo1 : Blo0;
    u16* Chi         = z ? Chi1 : Chi0;
    u16* Clo         = z ? Clo1 : Clo0;
    const float* rowscale = z ? rs1 : rs0;

    const int tid  = threadIdx.x;
    const int lane = tid & 63;
    const int wid  = tid >> 6;
    const int wm   = wid >> 1, wn = wid & 1;
    const int bm   = blockIdx.x * 128;
    const int bn   = blockIdx.y * 128;

    f32x4 acc[4][4];
#pragma unroll
    for (int i = 0; i < 4; ++i)
#pragma unroll
        for (int j = 0; j < 4; ++j) acc[i][j] = (f32x4){0.f, 0.f, 0.f, 0.f};

    const int gsw  = ((lane >> 2) & 3) ^ ((lane >> 4) & 3);
    const int gsta = ((lane & 3) ^ gsw) << 4;
    const int sl   = (lane & 3) ^ ((lane >> 2) & 3);
    const int hi4  = lane >> 4;
    const int gsel = ((hi4 ^ sl) << 4);
    const int frow = lane & 15;

    for (int k0 = 0; k0 < 256; k0 += 32) {
        if (k0) __syncthreads();

#pragma unroll
        for (int p = 0; p < 2; ++p) {
            int c   = p * 4 + wid;
            int row = c * 16 + (lane >> 2);
            size_t rb = (size_t)(bn + row) * ldb + (size_t)k0 * 2 + gsta;
            gl_lds16((const char*)Bhi + rb, smem + 16384 + c * 1024);
            gl_lds16((const char*)Blo + rb, smem + 24576 + c * 1024);
        }
        if (AMODE == 0) {
            const u16* Ah = (const u16*)Aptr;
#pragma unroll
            for (int p = 0; p < 2; ++p) {
                int c   = p * 4 + wid;
                int row = c * 16 + (lane >> 2);
                int grow = bm + row; if (grow >= M) grow = M - 1;
                size_t rb = (size_t)grow * 512 + (size_t)k0 * 2 + gsta;
                gl_lds16((const char*)Ah  + rb, smem + c * 1024);
                gl_lds16((const char*)Alo + rb, smem + 8192 + c * 1024);
            }
        } else {
            const float* Af = (const float*)Aptr;
            int row  = tid >> 1;
            int half = tid & 1;
            int grow = bm + row; if (grow >= M) grow = M - 1;
            const float* srcp = Af + (size_t)grow * 256 + k0 + half * 16;
            float vv[16];
            *(float4*)(vv + 0)  = *(const float4*)(srcp + 0);
            *(float4*)(vv + 4)  = *(const float4*)(srcp + 4);
            *(float4*)(vv + 8)  = *(const float4*)(srcp + 8);
            *(float4*)(vv + 12) = *(const float4*)(srcp + 12);
            u16 h[16], l[16];
#pragma unroll
            for (int i = 0; i < 16; ++i) {
                h[i] = f2bf(vv[i]);
                l[i] = f2bf(vv[i] - bf2f(h[i]));
            }
            int swz = (row & 3) ^ ((row >> 2) & 3);
            char* dh = smem + row * 64;
            char* dl = smem + 8192 + row * 64;
            st16(dh + (((half * 2 + 0) ^ swz) << 4), h + 0);
            st16(dh + (((half * 2 + 1) ^ swz) << 4), h + 8);
            st16(dl + (((half * 2 + 0) ^ swz) << 4), l + 0);
            st16(dl + (((half * 2 + 1) ^ swz) << 4), l + 8);
        }
        __syncthreads();

        bf16x8 ah[4], al[4], bh[4], bl[4];
#pragma unroll
        for (int fm = 0; fm < 4; ++fm) {
            int r = wm * 64 + fm * 16 + frow;
            ah[fm] = *(const bf16x8*)(smem + r * 64 + gsel);
            al[fm] = *(const bf16x8*)(smem + 8192 + r * 64 + gsel);
        }
#pragma unroll
        for (int fn = 0; fn < 4; ++fn) {
            int r = wn * 64 + fn * 16 + frow;
            bh[fn] = *(const bf16x8*)(smem + 16384 + r * 64 + gsel);
            bl[fn] = *(const bf16x8*)(smem + 24576 + r * 64 + gsel);
        }
#pragma unroll
        for (int fm = 0; fm < 4; ++fm)
#pragma unroll
            for (int fn = 0; fn < 4; ++fn)
                acc[fm][fn] = __builtin_amdgcn_mfma_f32_16x16x32_bf16(ah[fm], bh[fn], acc[fm][fn], 0, 0, 0);
#pragma unroll
        for (int fm = 0; fm < 4; ++fm)
#pragma unroll
            for (int fn = 0; fn < 4; ++fn)
                acc[fm][fn] = __builtin_amdgcn_mfma_f32_16x16x32_bf16(ah[fm], bl[fn], acc[fm][fn], 0, 0, 0);
#pragma unroll
        for (int fm = 0; fm < 4; ++fm)
#pragma unroll
            for (int fn = 0; fn < 4; ++fn)
                acc[fm][fn] = __builtin_amdgcn_mfma_f32_16x16x32_bf16(al[fm], bh[fn], acc[fm][fn], 0, 0, 0);
    }

#pragma unroll
    for (int fm = 0; fm < 4; ++fm) {
#pragma unroll
        for (int q = 0; q < 4; ++q) {
            int row = bm + wm * 64 + fm * 16 + hi4 * 4 + q;
            if (row < M) {
                float s = rowscale ? rowscale[row] : 1.0f;
#pragma unroll
                for (int fn = 0; fn < 4; ++fn) {
                    int col = bn + wn * 64 + fn * 16 + frow;
                    float v = acc[fm][fn][q] * s;
                    u16 hb = f2bf(v);
                    Chi[(size_t)row * N + col] = hb;
                    Clo[(size_t)row * N + col] = f2bf(v - bf2f(hb));
                }
            }
        }
    }
}

// ---------------- layer-1 aggregation (256-dim), fwd+bwd merged, ReLU+bias ----------------
// out[v] = relu( dinv[v]*( sum_{u in N(v)} ghi[u] + (ghi[v]+glo[v]) ) + b )
__global__ __launch_bounds__(256)
void k_agg1(const u16* __restrict__ ghf, const u16* __restrict__ glf,
            const u16* __restrict__ ghb, const u16* __restrict__ glb,
            const int* __restrict__ off_f, const int* __restrict__ lst_f,
            const int* __restrict__ off_b, const int* __restrict__ lst_b,
            const float* __restrict__ dinv_f, const float* __restrict__ dinv_b,
            const float* __restrict__ b_f, const float* __restrict__ b_b,
            u16* __restrict__ ohf, u16* __restrict__ olf,
            u16* __restrict__ ohb, u16* __restrict__ olb, int n)
{
    int nb = gridDim.x >> 1;
    int stack = blockIdx.x >= nb;
    int bx = stack ? (blockIdx.x - nb) : blockIdx.x;
    const u16* gh = stack ? ghb : ghf;
    const u16* gl = stack ? glb : glf;
    const int* off = stack ? off_b : off_f;
    const int* lst = stack ? lst_b : lst_f;
    const float* dinv = stack ? dinv_b : dinv_f;
    const float* bias = stack ? b_b : b_f;
    u16* oh = stack ? ohb : ohf;
    u16* ol = stack ? olb : olf;

    int wv = threadIdx.x >> 6, lane = threadIdx.x & 63;
    int v = bx * 4 + wv;
    if (v >= n) return;
    int c4 = lane * 4;

    ushort4 sh = *(const ushort4*)(gh + (size_t)v * 256 + c4);
    ushort4 sl = *(const ushort4*)(gl + (size_t)v * 256 + c4);
    float a0 = bf2f(sh.x) + bf2f(sl.x);
    float a1 = bf2f(sh.y) + bf2f(sl.y);
    float a2 = bf2f(sh.z) + bf2f(sl.z);
    float a3 = bf2f(sh.w) + bf2f(sl.w);

    int s0 = off[v], s1 = off[v + 1];
    int j = s0;
    for (; j + 4 <= s1; j += 4) {
        int u0 = lst[j], u1 = lst[j + 1], u2 = lst[j + 2], u3 = lst[j + 3];
        ushort4 m0 = *(const ushort4*)(gh + (size_t)u0 * 256 + c4);
        ushort4 m1 = *(const ushort4*)(gh + (size_t)u1 * 256 + c4);
        ushort4 m2 = *(const ushort4*)(gh + (size_t)u2 * 256 + c4);
        ushort4 m3 = *(const ushort4*)(gh + (size_t)u3 * 256 + c4);
        a0 += bf2f(m0.x) + bf2f(m1.x) + bf2f(m2.x) + bf2f(m3.x);
        a1 += bf2f(m0.y) + bf2f(m1.y) + bf2f(m2.y) + bf2f(m3.y);
        a2 += bf2f(m0.z) + bf2f(m1.z) + bf2f(m2.z) + bf2f(m3.z);
        a3 += bf2f(m0.w) + bf2f(m1.w) + bf2f(m2.w) + bf2f(m3.w);
    }
    for (; j < s1; ++j) {
        int u = lst[j];
        ushort4 m = *(const ushort4*)(gh + (size_t)u * 256 + c4);
        a0 += bf2f(m.x); a1 += bf2f(m.y); a2 += bf2f(m.z); a3 += bf2f(m.w);
    }
    float sc = dinv[v];
    float4 b4 = *(const float4*)(bias + c4);
    float o0 = fmaxf(a0 * sc + b4.x, 0.f);
    float o1 = fmaxf(a1 * sc + b4.y, 0.f);
    float o2 = fmaxf(a2 * sc + b4.z, 0.f);
    float o3 = fmaxf(a3 * sc + b4.w, 0.f);
    ushort4 rh, rl;
    rh.x = f2bf(o0); rl.x = f2bf(o0 - bf2f(rh.x));
    rh.y = f2bf(o1); rl.y = f2bf(o1 - bf2f(rh.y));
    rh.z = f2bf(o2); rl.z = f2bf(o2 - bf2f(rh.z));
    rh.w = f2bf(o3); rl.w = f2bf(o3 - bf2f(rh.w));
    *(ushort4*)(oh + (size_t)v * 256 + c4) = rh;
    *(ushort4*)(ol + (size_t)v * 256 + c4) = rl;
}

// ---------------- final aggregation (128-dim, both stacks) -> f32 out ----------------
// out[v] = dinv_f[v]*(sum yf[u] + yf[v]) + dinv_b[v]*(sum yb[u] + yb[v]) + cvec
__global__ __launch_bounds__(256)
void k_agg2(const u16* __restrict__ yfh, const u16* __restrict__ yfl,
            const u16* __restrict__ ybh, const u16* __restrict__ ybl,
            const int* __restrict__ off_f, const int* __restrict__ lst_f,
            const int* __restrict__ off_b, const int* __restrict__ lst_b,
            const float* __restrict__ dinv_f, const float* __restrict__ dinv_b,
            const float* __restrict__ cvec, float* __restrict__ out, int n)
{
    int wv = threadIdx.x >> 6, lane = threadIdx.x & 63;
    int v = blockIdx.x * 4 + wv;
    if (v >= n) return;
    int c2 = lane * 2;

    // forward
    ushort2 sh = *(const ushort2*)(yfh + (size_t)v * 128 + c2);
    ushort2 sl = *(const ushort2*)(yfl + (size_t)v * 128 + c2);
    float a0 = bf2f(sh.x) + bf2f(sl.x);
    float a1 = bf2f(sh.y) + bf2f(sl.y);
    {
        int s0 = off_f[v], s1 = off_f[v + 1];
        int j = s0;
        for (; j + 4 <= s1; j += 4) {
            int u0 = lst_f[j], u1 = lst_f[j + 1], u2 = lst_f[j + 2], u3 = lst_f[j + 3];
            ushort2 m0 = *(const ushort2*)(yfh + (size_t)u0 * 128 + c2);
            ushort2 m1 = *(const ushort2*)(yfh + (size_t)u1 * 128 + c2);
            ushort2 m2 = *(const ushort2*)(yfh + (size_t)u2 * 128 + c2);
            ushort2 m3 = *(const ushort2*)(yfh + (size_t)u3 * 128 + c2);
            a0 += bf2f(m0.x) + bf2f(m1.x) + bf2f(m2.x) + bf2f(m3.x);
            a1 += bf2f(m0.y) + bf2f(m1.y) + bf2f(m2.y) + bf2f(m3.y);
        }
        for (; j < s1; ++j) {
            int u = lst_f[j];
            ushort2 m = *(const ushort2*)(yfh + (size_t)u * 128 + c2);
            a0 += bf2f(m.x); a1 += bf2f(m.y);
        }
    }
    float o0 = a0 * dinv_f[v];
    float o1 = a1 * dinv_f[v];

    // backward
    ushort2 th = *(const ushort2*)(ybh + (size_t)v * 128 + c2);
    ushort2 tl = *(const ushort2*)(ybl + (size_t)v * 128 + c2);
    float b0 = bf2f(th.x) + bf2f(tl.x);
    float b1 = bf2f(th.y) + bf2f(tl.y);
    {
        int s0 = off_b[v], s1 = off_b[v + 1];
        int j = s0;
        for (; j + 4 <= s1; j += 4) {
            int u0 = lst_b[j], u1 = lst_b[j + 1], u2 = lst_b[j + 2], u3 = lst_b[j + 3];
            ushort2 m0 = *(const ushort2*)(ybh + (size_t)u0 * 128 + c2);
            ushort2 m1 = *(const ushort2*)(ybh + (size_t)u1 * 128 + c2);
            ushort2 m2 = *(const ushort2*)(ybh + (size_t)u2 * 128 + c2);
            ushort2 m3 = *(const ushort2*)(ybh + (size_t)u3 * 128 + c2);
            b0 += bf2f(m0.x) + bf2f(m1.x) + bf2f(m2.x) + bf2f(m3.x);
            b1 += bf2f(m0.y) + bf2f(m1.y) + bf2f(m2.y) + bf2f(m3.y);
        }
        for (; j < s1; ++j) {
            int u = lst_b[j];
            ushort2 m = *(const ushort2*)(ybh + (size_t)u * 128 + c2);
            b0 += bf2f(m.x); b1 += bf2f(m.y);
        }
    }
    o0 += b0 * dinv_b[v] + cvec[c2 + 0];
    o1 += b1 * dinv_b[v] + cvec[c2 + 1];

    float2 o; o.x = o0; o.y = o1;
    *(float2*)(out + (size_t)v * 128 + c2) = o;
}

extern "C" void kernel_launch(void* const* d_in, const int* in_sizes, int n_in,
                              void* d_out, int out_size, void* d_ws, size_t ws_size,
                              hipStream_t stream) {
    const float* x    = (const float*)d_in[0];
    const int*   ei   = (const int*)d_in[1];
    const float* Wf1  = (const float*)d_in[2];
    const float* bf1  = (const float*)d_in[3];
    const float* Wf2  = (const float*)d_in[4];
    const float* bf2  = (const float*)d_in[5];
    const float* Wb1  = (const float*)d_in[6];
    const float* bb1  = (const float*)d_in[7];
    const float* Wb2  = (const float*)d_in[8];
    const float* bb2  = (const float*)d_in[9];
    const float* Wfin = (const float*)d_in[10];
    const float* bfin = (const float*)d_in[11];
    float* out = (float*)d_out;

    const int n = in_sizes[0] / 256;   // 20000
    const int E = in_sizes[1] / 2;     // 320000
    const int* src = ei;
    const int* dst = ei + E;

    char* p = (char*)d_ws;
    auto take = [&](size_t bytes) -> void* {
        void* q = (void*)p;
        p += (bytes + 255) & ~(size_t)255;
        return q;
    };
    // activation planes
    u16* P1f_h = (u16*)take((size_t)n * 256 * 2);
    u16* P1f_l = (u16*)take((size_t)n * 256 * 2);
    u16* P1b_h = (u16*)take((size_t)n * 256 * 2);
    u16* P1b_l = (u16*)take((size_t)n * 256 * 2);
    u16* P2f_h = (u16*)take((size_t)n * 256 * 2);
    u16* P2f_l = (u16*)take((size_t)n * 256 * 2);
    u16* P2b_h = (u16*)take((size_t)n * 256 * 2);
    u16* P2b_l = (u16*)take((size_t)n * 256 * 2);
    u16* Yf_h  = (u16*)take((size_t)n * 128 * 2);
    u16* Yf_l  = (u16*)take((size_t)n * 128 * 2);
    u16* Yb_h  = (u16*)take((size_t)n * 128 * 2);
    u16* Yb_l  = (u16*)take((size_t)n * 128 * 2);
    // weight planes
    u16* w1f_h = (u16*)take(65536 * 2); u16* w1f_l = (u16*)take(65536 * 2);
    u16* w2f_h = (u16*)take(65536 * 2); u16* w2f_l = (u16*)take(65536 * 2);
    u16* w1b_h = (u16*)take(65536 * 2); u16* w1b_l = (u16*)take(65536 * 2);
    u16* w2b_h = (u16*)take(65536 * 2); u16* w2b_l = (u16*)take(65536 * 2);
    u16* wfin_h = (u16*)take(65536 * 2); u16* wfin_l = (u16*)take(65536 * 2);
    float* cvec = (float*)take(128 * sizeof(float));
    // CSR
    int*   deg_f  = (int*)take((size_t)n * sizeof(int));
    int*   deg_b  = (int*)take((size_t)n * sizeof(int));
    int*   off_f  = (int*)take((size_t)(n + 1) * sizeof(int));
    int*   off_b  = (int*)take((size_t)(n + 1) * sizeof(int));
    int*   cur_f  = (int*)take((size_t)n * sizeof(int));
    int*   cur_b  = (int*)take((size_t)n * sizeof(int));
    int*   lst_f  = (int*)take((size_t)E * sizeof(int));
    int*   lst_b  = (int*)take((size_t)E * sizeof(int));
    float* dinv_f = (float*)take((size_t)n * sizeof(float));
    float* dinv_b = (float*)take((size_t)n * sizeof(float));

    hipMemsetAsync(deg_f, 0, (size_t)n * sizeof(int), stream);
    hipMemsetAsync(deg_b, 0, (size_t)n * sizeof(int), stream);

    int eb = (E + 255) / 256;
    k_deg<<<eb, 256, 0, stream>>>(src, dst, deg_f, deg_b, E);
    k_scan<<<2, 1024, 0, stream>>>(deg_f, off_f, cur_f, deg_b, off_b, cur_b, n);
    k_fill<<<eb, 256, 0, stream>>>(src, dst, cur_f, cur_b, lst_f, lst_b, E);
    k_dinv<<<(n + 255) / 256, 256, 0, stream>>>(deg_f, deg_b, dinv_f, dinv_b, n);

    int wb = (65536 + 255) / 256;
    k_wsplit<<<wb, 256, 0, stream>>>(Wf1,  w1f_h, w1f_l, 256, 256);
    k_wsplit<<<wb, 256, 0, stream>>>(Wf2,  w2f_h, w2f_l, 256, 256);
    k_wsplit<<<wb, 256, 0, stream>>>(Wb1,  w1b_h, w1b_l, 256, 256);
    k_wsplit<<<wb, 256, 0, stream>>>(Wb2,  w2b_h, w2b_l, 256, 256);
    k_wsplit<<<wb, 256, 0, stream>>>(Wfin, wfin_h, wfin_l, 512, 128);
    k_cvec<<<1, 128, 0, stream>>>(bfin, bf2, bb2, Wfin, cvec);

    const int gx = (n + 127) / 128;       // 157
    dim3 gBig(gx, 2, 2);                  // N=256, fwd+bwd
    dim3 gFin(gx, 1, 2);                  // N=128, fwd+bwd
    int ab = (n + 3) / 4;

    // G1: h1 = (x @ W1) * dinv   (both stacks)
    k_gemm2<1><<<gBig, 256, 0, stream>>>(x, x, nullptr, nullptr,
        w1f_h, w1f_l, w1b_h, w1b_l, 512,
        P1f_h, P1f_l, P1b_h, P1b_l, dinv_f, dinv_b, n, 256);
    // A1: z1 = relu(dinv * agg(h1) + b1)  (both stacks)
    k_agg1<<<2 * ab, 256, 0, stream>>>(P1f_h, P1f_l, P1b_h, P1b_l,
        off_f, lst_f, off_b, lst_b, dinv_f, dinv_b, bf1, bb1,
        P2f_h, P2f_l, P2b_h, P2b_l, n);
    // G2: h2 = (z1 @ W2) * dinv   (both stacks)
    k_gemm2<0><<<gBig, 256, 0, stream>>>(P2f_h, P2b_h, P2f_l, P2b_l,
        w2f_h, w2f_l, w2b_h, w2b_l, 512,
        P1f_h, P1f_l, P1b_h, P1b_l, dinv_f, dinv_b, n, 256);
    // Gfin: y = h2 @ Wfin_half    (both stacks, no rowscale)
    k_gemm2<0><<<gFin, 256, 0, stream>>>(P1f_h, P1b_h, P1f_l, P1b_l,
        wfin_h, wfin_l, wfin_h + 256, wfin_l + 256, 1024,
        Yf_h, Yf_l, Yb_h, Yb_l, nullptr, nullptr, n, 128);
    // A2: out = dinv_f*agg_f(yf) + dinv_b*agg_b(yb) + cvec
    k_agg2<<<ab, 256, 0, stream>>>(Yf_h, Yf_l, Yb_h, Yb_l,
        off_f, lst_f, off_b, lst_b, dinv_f, dinv_b, cvec, out, n);
}

// Round 9
// 337.650 us; speedup vs baseline: 1.8761x; 1.0819x over previous
//
#include <hip/hip_runtime.h>

typedef unsigned int   u32;
typedef unsigned short u16;
typedef __attribute__((ext_vector_type(8))) short bf16x8;
typedef __attribute__((ext_vector_type(4))) float f32x4;

// ---------- bf16 helpers ----------
__device__ __forceinline__ u16 f2bf(float f) {
    u32 u = __float_as_uint(f);
    u32 r = u + 0x7fffu + ((u >> 16) & 1u);
    return (u16)(r >> 16);
}
__device__ __forceinline__ float bf2f(u16 h) {
    return __uint_as_float(((u32)h) << 16);
}
__device__ __forceinline__ float lof(u32 q) { return __uint_as_float(q << 16); }
__device__ __forceinline__ float hif(u32 q) { return __uint_as_float(q & 0xffff0000u); }
__device__ __forceinline__ u32 pk(float a, float b) {
    return (u32)f2bf(a) | ((u32)f2bf(b) << 16);
}
__device__ __forceinline__ void gl_lds16(const void* g, void* l) {
    __builtin_amdgcn_global_load_lds(
        (const __attribute__((address_space(1))) u32*)g,
        (__attribute__((address_space(3))) u32*)l, 16, 0, 0);
}
__device__ __forceinline__ void st16(void* dst, const u16* h) {
    uint4 q;
    q.x = (u32)h[0] | ((u32)h[1] << 16);
    q.y = (u32)h[2] | ((u32)h[3] << 16);
    q.z = (u32)h[4] | ((u32)h[5] << 16);
    q.w = (u32)h[6] | ((u32)h[7] << 16);
    *(uint4*)dst = q;
}

// ---------------- degree count ----------------
__global__ __launch_bounds__(256)
void k_deg(const int* __restrict__ src, const int* __restrict__ dst,
           int* __restrict__ deg_f, int* __restrict__ deg_b, int E) {
    int e = blockIdx.x * 256 + threadIdx.x;
    if (e < E) {
        atomicAdd(&deg_f[dst[e]], 1);
        atomicAdd(&deg_b[src[e]], 1);
    }
}

// ---------------- exclusive scan + dinv (1 block per direction) ----------------
__global__ __launch_bounds__(1024)
void k_scan(const int* __restrict__ deg_f, int* __restrict__ off_f, int* __restrict__ cur_f,
            const int* __restrict__ deg_b, int* __restrict__ off_b, int* __restrict__ cur_b,
            float* __restrict__ dinv_f, float* __restrict__ dinv_b, int n) {
    __shared__ int sm[1024];
    const int T = 1024;
    int t = threadIdx.x;
    const int* deg = blockIdx.x ? deg_b : deg_f;
    int* off = blockIdx.x ? off_b : off_f;
    int* cur = blockIdx.x ? cur_b : cur_f;
    float* dinv = blockIdx.x ? dinv_b : dinv_f;

    int chunk = (n + T - 1) / T;
    int base = t * chunk;
    int sum = 0;
    for (int i = 0; i < chunk; ++i) {
        int idx = base + i;
        if (idx < n) {
            int d = deg[idx];
            sum += d;
            dinv[idx] = rsqrtf((float)(d + 1));
        }
    }
    sm[t] = sum;
    __syncthreads();
    for (int s = 1; s < T; s <<= 1) {
        int v = (t >= s) ? sm[t - s] : 0;
        __syncthreads();
        sm[t] += v;
        __syncthreads();
    }
    int run = sm[t] - sum;
    for (int i = 0; i < chunk; ++i) {
        int idx = base + i;
        if (idx < n) {
            off[idx] = run;
            cur[idx] = run;
            run += deg[idx];
        }
    }
    if (t == T - 1) off[n] = sm[T - 1];
}

// ---------------- CSR fill ----------------
__global__ __launch_bounds__(256)
void k_fill(const int* __restrict__ src, const int* __restrict__ dst,
            int* __restrict__ cur_f, int* __restrict__ cur_b,
            int* __restrict__ lst_f, int* __restrict__ lst_b, int E) {
    int e = blockIdx.x * 256 + threadIdx.x;
    if (e < E) {
        int s = src[e], d = dst[e];
        int pf = atomicAdd(&cur_f[d], 1);
        lst_f[pf] = s;
        int pb = atomicAdd(&cur_b[s], 1);
        lst_b[pb] = d;
    }
}

// ---------------- all 5 weight transposes + hi/lo split in one launch ----------------
// 256 blocks per weight (65536 elements each); which = blockIdx>>8 is block-uniform.
__global__ __launch_bounds__(256)
void k_wsplit5(const float* __restrict__ W0, const float* __restrict__ W1,
               const float* __restrict__ W2, const float* __restrict__ W3,
               const float* __restrict__ W4,
               u16* __restrict__ h0, u16* __restrict__ l0,
               u16* __restrict__ h1, u16* __restrict__ l1,
               u16* __restrict__ h2, u16* __restrict__ l2,
               u16* __restrict__ h3, u16* __restrict__ l3,
               u16* __restrict__ h4, u16* __restrict__ l4)
{
    int which = blockIdx.x >> 8;
    int sub = ((blockIdx.x & 255) << 8) | threadIdx.x;   // 0..65535
    const float* W; u16 *H, *L; int kshift, N;
    switch (which) {
        case 0: W = W0; H = h0; L = l0; kshift = 8; N = 256; break;
        case 1: W = W1; H = h1; L = l1; kshift = 8; N = 256; break;
        case 2: W = W2; H = h2; L = l2; kshift = 8; N = 256; break;
        case 3: W = W3; H = h3; L = l3; kshift = 8; N = 256; break;
        default: W = W4; H = h4; L = l4; kshift = 9; N = 128; break;
    }
    int ni = sub >> kshift;
    int ki = sub & ((1 << kshift) - 1);
    float v = W[(size_t)ki * N + ni];
    u16 hh = f2bf(v);
    H[sub] = hh;
    L[sub] = f2bf(v - bf2f(hh));
}

// ---------------- cvec = bfin + bf2^T Wfin[0:256] + bb2^T Wfin[256:512] ----------------
__global__ __launch_bounds__(256)
void k_cvec(const float* __restrict__ bfin, const float* __restrict__ bf2,
            const float* __restrict__ bb2, const float* __restrict__ Wfin,
            float* __restrict__ cvec) {
    __shared__ float red[256];
    int j = blockIdx.x;        // 0..127
    int t = threadIdx.x;       // 0..255
    float s = bf2[t] * Wfin[(size_t)t * 128 + j]
            + bb2[t] * Wfin[(size_t)(t + 256) * 128 + j];
    red[t] = s;
    __syncthreads();
    for (int st = 128; st > 0; st >>= 1) {
        if (t < st) red[t] += red[t + st];
        __syncthreads();
    }
    if (t == 0) cvec[j] = red[0] + bfin[j];
}

// ---------------- MFMA GEMM (fwd+bwd merged via blockIdx.z) ----------------
// C[M,N] = A[M,256] @ Bt[N,256]^T ; tile 128x128, BK=32, 4 waves (2x2).
// AMODE 0: A = bf16 hi plane [M][256] (gload_lds);  AMODE 1: A = f32 (reg split).
// PASS3: include al*bh pass (needs A lo plane).  WLO: write C lo plane.
template<int AMODE, int PASS3, int WLO>
__global__ __launch_bounds__(256)
void k_gemm2(const void* __restrict__ A0, const void* __restrict__ A1p,
             const u16* __restrict__ Alo0, const u16* __restrict__ Alo1,
             const u16* __restrict__ Bhi0, const u16* __restrict__ Blo0,
             const u16* __restrict__ Bhi1, const u16* __restrict__ Blo1, int ldb,
             u16* __restrict__ Chi0, u16* __restrict__ Clo0,
             u16* __restrict__ Chi1, u16* __restrict__ Clo1,
             const float* __restrict__ rs0, const float* __restrict__ rs1,
             int M, int N)
{
    constexpr int ALO = 8192;
    constexpr int BHI = PASS3 ? 16384 : 8192;
    constexpr int BLO = BHI + 8192;
    __shared__ char smem[PASS3 ? 32768 : 24576];

    const int z = blockIdx.z;
    const void* Aptr = z ? A1p : A0;
    const u16* Alo   = z ? Alo1 : Alo0;
    const u16* Bhi   = z ? Bhi1 : Bhi0;
    const u16* Blo   = z ? Blo1 : Blo0;
    u16* Chi         = z ? Chi1 : Chi0;
    u16* Clo         = z ? Clo1 : Clo0;
    const float* rowscale = z ? rs1 : rs0;

    const int tid  = threadIdx.x;
    const int lane = tid & 63;
    const int wid  = tid >> 6;
    const int wm   = wid >> 1, wn = wid & 1;
    const int bm   = blockIdx.x * 128;
    const int bn   = blockIdx.y * 128;

    f32x4 acc[4][4];
#pragma unroll
    for (int i = 0; i < 4; ++i)
#pragma unroll
        for (int j = 0; j < 4; ++j) acc[i][j] = (f32x4){0.f, 0.f, 0.f, 0.f};

    const int gsw  = ((lane >> 2) & 3) ^ ((lane >> 4) & 3);
    const int gsta = ((lane & 3) ^ gsw) << 4;
    const int sl   = (lane & 3) ^ ((lane >> 2) & 3);
    const int hi4  = lane >> 4;
    const int gsel = ((hi4 ^ sl) << 4);
    const int frow = lane & 15;

    for (int k0 = 0; k0 < 256; k0 += 32) {
        if (k0) __syncthreads();

#pragma unroll
        for (int p = 0; p < 2; ++p) {
            int c   = p * 4 + wid;
            int row = c * 16 + (lane >> 2);
            size_t rb = (size_t)(bn + row) * ldb + (size_t)k0 * 2 + gsta;
            gl_lds16((const char*)Bhi + rb, smem + BHI + c * 1024);
            gl_lds16((const char*)Blo + rb, smem + BLO + c * 1024);
        }
        if (AMODE == 0) {
            const u16* Ah = (const u16*)Aptr;
#pragma unroll
            for (int p = 0; p < 2; ++p) {
                int c   = p * 4 + wid;
                int row = c * 16 + (lane >> 2);
                int grow = bm + row; if (grow >= M) grow = M - 1;
                size_t rb = (size_t)grow * 512 + (size_t)k0 * 2 + gsta;
                gl_lds16((const char*)Ah + rb, smem + c * 1024);
                if (PASS3)
                    gl_lds16((const char*)Alo + rb, smem + ALO + c * 1024);
            }
        } else {
            const float* Af = (const float*)Aptr;
            int row  = tid >> 1;
            int half = tid & 1;
            int grow = bm + row; if (grow >= M) grow = M - 1;
            const float* srcp = Af + (size_t)grow * 256 + k0 + half * 16;
            float vv[16];
            *(float4*)(vv + 0)  = *(const float4*)(srcp + 0);
            *(float4*)(vv + 4)  = *(const float4*)(srcp + 4);
            *(float4*)(vv + 8)  = *(const float4*)(srcp + 8);
            *(float4*)(vv + 12) = *(const float4*)(srcp + 12);
            u16 h[16], l[16];
#pragma unroll
            for (int i = 0; i < 16; ++i) {
                h[i] = f2bf(vv[i]);
                l[i] = f2bf(vv[i] - bf2f(h[i]));
            }
            int swz = (row & 3) ^ ((row >> 2) & 3);
            char* dh = smem + row * 64;
            st16(dh + (((half * 2 + 0) ^ swz) << 4), h + 0);
            st16(dh + (((half * 2 + 1) ^ swz) << 4), h + 8);
            if (PASS3) {
                char* dl = smem + ALO + row * 64;
                st16(dl + (((half * 2 + 0) ^ swz) << 4), l + 0);
                st16(dl + (((half * 2 + 1) ^ swz) << 4), l + 8);
            }
        }
        __syncthreads();

        bf16x8 ah[4], al[4], bh[4], bl[4];
#pragma unroll
        for (int fm = 0; fm < 4; ++fm) {
            int r = wm * 64 + fm * 16 + frow;
            ah[fm] = *(const bf16x8*)(smem + r * 64 + gsel);
            if (PASS3) al[fm] = *(const bf16x8*)(smem + ALO + r * 64 + gsel);
        }
#pragma unroll
        for (int fn = 0; fn < 4; ++fn) {
            int r = wn * 64 + fn * 16 + frow;
            bh[fn] = *(const bf16x8*)(smem + BHI + r * 64 + gsel);
            bl[fn] = *(const bf16x8*)(smem + BLO + r * 64 + gsel);
        }
#pragma unroll
        for (int fm = 0; fm < 4; ++fm)
#pragma unroll
            for (int fn = 0; fn < 4; ++fn)
                acc[fm][fn] = __builtin_amdgcn_mfma_f32_16x16x32_bf16(ah[fm], bh[fn], acc[fm][fn], 0, 0, 0);
#pragma unroll
        for (int fm = 0; fm < 4; ++fm)
#pragma unroll
            for (int fn = 0; fn < 4; ++fn)
                acc[fm][fn] = __builtin_amdgcn_mfma_f32_16x16x32_bf16(ah[fm], bl[fn], acc[fm][fn], 0, 0, 0);
        if (PASS3) {
#pragma unroll
            for (int fm = 0; fm < 4; ++fm)
#pragma unroll
                for (int fn = 0; fn < 4; ++fn)
                    acc[fm][fn] = __builtin_amdgcn_mfma_f32_16x16x32_bf16(al[fm], bh[fn], acc[fm][fn], 0, 0, 0);
        }
    }

#pragma unroll
    for (int fm = 0; fm < 4; ++fm) {
#pragma unroll
        for (int q = 0; q < 4; ++q) {
            int row = bm + wm * 64 + fm * 16 + hi4 * 4 + q;
            if (row < M) {
                float s = rowscale ? rowscale[row] : 1.0f;
#pragma unroll
                for (int fn = 0; fn < 4; ++fn) {
                    int col = bn + wn * 64 + fn * 16 + frow;
                    float v = acc[fm][fn][q] * s;
                    u16 hb = f2bf(v);
                    Chi[(size_t)row * N + col] = hb;
                    if (WLO) Clo[(size_t)row * N + col] = f2bf(v - bf2f(hb));
                }
            }
        }
    }
}

// ---------------- layer-1 aggregation: 2 nodes/wave, hi-only output ----------------
// z1[v] = relu( dinv[v]*( sum_{u} gh[u] + (gh[v]+gl[v]) ) + b )
__global__ __launch_bounds__(256)
void k_agg1(const u16* __restrict__ ghf, const u16* __restrict__ glf,
            const u16* __restrict__ ghb, const u16* __restrict__ glb,
            const int* __restrict__ off_f, const int* __restrict__ lst_f,
            const int* __restrict__ off_b, const int* __restrict__ lst_b,
            const float* __restrict__ dinv_f, const float* __restrict__ dinv_b,
            const float* __restrict__ b_f, const float* __restrict__ b_b,
            u16* __restrict__ ozf, u16* __restrict__ ozb, int n)
{
    int nb = gridDim.x >> 1;
    int stack = blockIdx.x >= nb;
    int bx = stack ? (blockIdx.x - nb) : blockIdx.x;
    const u16* gh = stack ? ghb : ghf;
    const u16* gl = stack ? glb : glf;
    const int* off = stack ? off_b : off_f;
    const int* lst = stack ? lst_b : lst_f;
    const float* dinv = stack ? dinv_b : dinv_f;
    const float* bias = stack ? b_b : b_f;
    u16* oz = stack ? ozb : ozf;

    int wv = threadIdx.x >> 6;
    int half = (threadIdx.x >> 5) & 1;
    int l = threadIdx.x & 31;
    int v = bx * 8 + wv * 2 + half;
    if (v >= n) return;
    int f0 = l * 8;                        // 8 features, 16 B per lane

    uint4 qh = *(const uint4*)(gh + (size_t)v * 256 + f0);
    uint4 ql = *(const uint4*)(gl + (size_t)v * 256 + f0);
    float a0 = lof(qh.x) + lof(ql.x), a1 = hif(qh.x) + hif(ql.x);
    float a2 = lof(qh.y) + lof(ql.y), a3 = hif(qh.y) + hif(ql.y);
    float a4 = lof(qh.z) + lof(ql.z), a5 = hif(qh.z) + hif(ql.z);
    float a6 = lof(qh.w) + lof(ql.w), a7 = hif(qh.w) + hif(ql.w);

    int s0 = off[v], s1 = off[v + 1];
    int j = s0;
    for (; j + 4 <= s1; j += 4) {
        int u0 = lst[j], u1 = lst[j + 1], u2 = lst[j + 2], u3 = lst[j + 3];
        uint4 m0 = *(const uint4*)(gh + (size_t)u0 * 256 + f0);
        uint4 m1 = *(const uint4*)(gh + (size_t)u1 * 256 + f0);
        uint4 m2 = *(const uint4*)(gh + (size_t)u2 * 256 + f0);
        uint4 m3 = *(const uint4*)(gh + (size_t)u3 * 256 + f0);
        a0 += lof(m0.x) + lof(m1.x) + lof(m2.x) + lof(m3.x);
        a1 += hif(m0.x) + hif(m1.x) + hif(m2.x) + hif(m3.x);
        a2 += lof(m0.y) + lof(m1.y) + lof(m2.y) + lof(m3.y);
        a3 += hif(m0.y) + hif(m1.y) + hif(m2.y) + hif(m3.y);
        a4 += lof(m0.z) + lof(m1.z) + lof(m2.z) + lof(m3.z);
        a5 += hif(m0.z) + hif(m1.z) + hif(m2.z) + hif(m3.z);
        a6 += lof(m0.w) + lof(m1.w) + lof(m2.w) + lof(m3.w);
        a7 += hif(m0.w) + hif(m1.w) + hif(m2.w) + hif(m3.w);
    }
    for (; j < s1; ++j) {
        int u = lst[j];
        uint4 m = *(const uint4*)(gh + (size_t)u * 256 + f0);
        a0 += lof(m.x); a1 += hif(m.x);
        a2 += lof(m.y); a3 += hif(m.y);
        a4 += lof(m.z); a5 += hif(m.z);
        a6 += lof(m.w); a7 += hif(m.w);
    }
    float sc = dinv[v];
    float4 bA = *(const float4*)(bias + f0);
    float4 bB = *(const float4*)(bias + f0 + 4);
    float o0 = fmaxf(a0 * sc + bA.x, 0.f), o1 = fmaxf(a1 * sc + bA.y, 0.f);
    float o2 = fmaxf(a2 * sc + bA.z, 0.f), o3 = fmaxf(a3 * sc + bA.w, 0.f);
    float o4 = fmaxf(a4 * sc + bB.x, 0.f), o5 = fmaxf(a5 * sc + bB.y, 0.f);
    float o6 = fmaxf(a6 * sc + bB.z, 0.f), o7 = fmaxf(a7 * sc + bB.w, 0.f);
    uint4 r;
    r.x = pk(o0, o1); r.y = pk(o2, o3); r.z = pk(o4, o5); r.w = pk(o6, o7);
    *(uint4*)(oz + (size_t)v * 256 + f0) = r;
}

// ---------------- final aggregation: dir-split lanes, hi-only Y -> f32 out ----------------
// out[v] = dinv_f[v]*(sum yf[u] + yf[v]) + dinv_b[v]*(sum yb[u] + yb[v]) + cvec
__global__ __launch_bounds__(256)
void k_agg2(const u16* __restrict__ yf, const u16* __restrict__ yb,
            const int* __restrict__ off_f, const int* __restrict__ lst_f,
            const int* __restrict__ off_b, const int* __restrict__ lst_b,
            const float* __restrict__ dinv_f, const float* __restrict__ dinv_b,
            const float* __restrict__ cvec, float* __restrict__ out, int n)
{
    int wv = threadIdx.x >> 6, lane = threadIdx.x & 63;
    int v = blockIdx.x * 4 + wv;
    if (v >= n) return;
    int dirb = lane >> 5;                  // 0: fwd lanes, 1: bwd lanes
    int l = lane & 31;
    int f0 = l * 4;                        // 4 features, 8 B per lane

    const u16* y   = dirb ? yb : yf;
    const int* off = dirb ? off_b : off_f;
    const int* lst = dirb ? lst_b : lst_f;
    float dv = dirb ? dinv_b[v] : dinv_f[v];

    uint2 q = *(const uint2*)(y + (size_t)v * 128 + f0);
    float a0 = lof(q.x), a1 = hif(q.x), a2 = lof(q.y), a3 = hif(q.y);

    int s0 = off[v], s1 = off[v + 1];
    int j = s0;
    for (; j + 4 <= s1; j += 4) {
        int u0 = lst[j], u1 = lst[j + 1], u2 = lst[j + 2], u3 = lst[j + 3];
        uint2 m0 = *(const uint2*)(y + (size_t)u0 * 128 + f0);
        uint2 m1 = *(const uint2*)(y + (size_t)u1 * 128 + f0);
        uint2 m2 = *(const uint2*)(y + (size_t)u2 * 128 + f0);
        uint2 m3 = *(const uint2*)(y + (size_t)u3 * 128 + f0);
        a0 += lof(m0.x) + lof(m1.x) + lof(m2.x) + lof(m3.x);
        a1 += hif(m0.x) + hif(m1.x) + hif(m2.x) + hif(m3.x);
        a2 += lof(m0.y) + lof(m1.y) + lof(m2.y) + lof(m3.y);
        a3 += hif(m0.y) + hif(m1.y) + hif(m2.y) + hif(m3.y);
    }
    for (; j < s1; ++j) {
        int u = lst[j];
        uint2 m = *(const uint2*)(y + (size_t)u * 128 + f0);
        a0 += lof(m.x); a1 += hif(m.x);
        a2 += lof(m.y); a3 += hif(m.y);
    }
    float o0 = a0 * dv, o1 = a1 * dv, o2 = a2 * dv, o3 = a3 * dv;
    o0 += __shfl_xor(o0, 32);
    o1 += __shfl_xor(o1, 32);
    o2 += __shfl_xor(o2, 32);
    o3 += __shfl_xor(o3, 32);
    if (dirb == 0) {
        float4 c4 = *(const float4*)(cvec + f0);
        float4 o;
        o.x = o0 + c4.x; o.y = o1 + c4.y; o.z = o2 + c4.z; o.w = o3 + c4.w;
        *(float4*)(out + (size_t)v * 128 + f0) = o;
    }
}

extern "C" void kernel_launch(void* const* d_in, const int* in_sizes, int n_in,
                              void* d_out, int out_size, void* d_ws, size_t ws_size,
                              hipStream_t stream) {
    const float* x    = (const float*)d_in[0];
    const int*   ei   = (const int*)d_in[1];
    const float* Wf1  = (const float*)d_in[2];
    const float* bf1  = (const float*)d_in[3];
    const float* Wf2  = (const float*)d_in[4];
    const float* bf2  = (const float*)d_in[5];
    const float* Wb1  = (const float*)d_in[6];
    const float* bb1  = (const float*)d_in[7];
    const float* Wb2  = (const float*)d_in[8];
    const float* bb2  = (const float*)d_in[9];
    const float* Wfin = (const float*)d_in[10];
    const float* bfin = (const float*)d_in[11];
    float* out = (float*)d_out;

    const int n = in_sizes[0] / 256;   // 20000
    const int E = in_sizes[1] / 2;     // 320000
    const int* src = ei;
    const int* dst = ei + E;

    char* p = (char*)d_ws;
    auto take = [&](size_t bytes) -> void* {
        void* q = (void*)p;
        p += (bytes + 255) & ~(size_t)255;
        return q;
    };
    // activation planes
    u16* P1f_h = (u16*)take((size_t)n * 256 * 2);
    u16* P1f_l = (u16*)take((size_t)n * 256 * 2);
    u16* P1b_h = (u16*)take((size_t)n * 256 * 2);
    u16* P1b_l = (u16*)take((size_t)n * 256 * 2);
    u16* Zf    = (u16*)take((size_t)n * 256 * 2);
    u16* Zb    = (u16*)take((size_t)n * 256 * 2);
    u16* H2f   = (u16*)take((size_t)n * 256 * 2);
    u16* H2b   = (u16*)take((size_t)n * 256 * 2);
    u16* Yf    = (u16*)take((size_t)n * 128 * 2);
    u16* Yb    = (u16*)take((size_t)n * 128 * 2);
    // weight planes
    u16* w1f_h = (u16*)take(65536 * 2); u16* w1f_l = (u16*)take(65536 * 2);
    u16* w2f_h = (u16*)take(65536 * 2); u16* w2f_l = (u16*)take(65536 * 2);
    u16* w1b_h = (u16*)take(65536 * 2); u16* w1b_l = (u16*)take(65536 * 2);
    u16* w2b_h = (u16*)take(65536 * 2); u16* w2b_l = (u16*)take(65536 * 2);
    u16* wfin_h = (u16*)take(65536 * 2); u16* wfin_l = (u16*)take(65536 * 2);
    float* cvec = (float*)take(128 * sizeof(float));
    // CSR
    int*   deg_f  = (int*)take((size_t)n * sizeof(int));
    int*   deg_b  = (int*)take((size_t)n * sizeof(int));
    int*   off_f  = (int*)take((size_t)(n + 1) * sizeof(int));
    int*   off_b  = (int*)take((size_t)(n + 1) * sizeof(int));
    int*   cur_f  = (int*)take((size_t)n * sizeof(int));
    int*   cur_b  = (int*)take((size_t)n * sizeof(int));
    int*   lst_f  = (int*)take((size_t)E * sizeof(int));
    int*   lst_b  = (int*)take((size_t)E * sizeof(int));
    float* dinv_f = (float*)take((size_t)n * sizeof(float));
    float* dinv_b = (float*)take((size_t)n * sizeof(float));

    hipMemsetAsync(deg_f, 0, (size_t)n * sizeof(int), stream);
    hipMemsetAsync(deg_b, 0, (size_t)n * sizeof(int), stream);

    int eb = (E + 255) / 256;
    k_deg<<<eb, 256, 0, stream>>>(src, dst, deg_f, deg_b, E);
    k_scan<<<2, 1024, 0, stream>>>(deg_f, off_f, cur_f, deg_b, off_b, cur_b,
                                   dinv_f, dinv_b, n);
    k_fill<<<eb, 256, 0, stream>>>(src, dst, cur_f, cur_b, lst_f, lst_b, E);
    k_wsplit5<<<1280, 256, 0, stream>>>(Wf1, Wf2, Wb1, Wb2, Wfin,
        w1f_h, w1f_l, w2f_h, w2f_l, w1b_h, w1b_l, w2b_h, w2b_l, wfin_h, wfin_l);
    k_cvec<<<128, 256, 0, stream>>>(bfin, bf2, bb2, Wfin, cvec);

    const int gx = (n + 127) / 128;       // 157
    dim3 gBig(gx, 2, 2);                  // N=256, fwd+bwd
    dim3 gFin(gx, 1, 2);                  // N=128, fwd+bwd
    int ab = (n + 3) / 4;
    int a1b = 2 * ((n + 7) / 8);

    // G1: h1 = (x @ W1) * dinv   (3-pass, hi+lo out)
    k_gemm2<1, 1, 1><<<gBig, 256, 0, stream>>>(x, x, nullptr, nullptr,
        w1f_h, w1f_l, w1b_h, w1b_l, 512,
        P1f_h, P1f_l, P1b_h, P1b_l, dinv_f, dinv_b, n, 256);
    // A1: z1 = relu(dinv * agg(h1) + b1)   (hi-only out)
    k_agg1<<<a1b, 256, 0, stream>>>(P1f_h, P1f_l, P1b_h, P1b_l,
        off_f, lst_f, off_b, lst_b, dinv_f, dinv_b, bf1, bb1, Zf, Zb, n);
    // G2: h2 = (z1 @ W2) * dinv   (2-pass, hi-only out)
    k_gemm2<0, 0, 0><<<gBig, 256, 0, stream>>>(Zf, Zb, nullptr, nullptr,
        w2f_h, w2f_l, w2b_h, w2b_l, 512,
        H2f, nullptr, H2b, nullptr, dinv_f, dinv_b, n, 256);
    // Gfin: y = h2 @ Wfin_half    (2-pass, hi-only out, no rowscale)
    k_gemm2<0, 0, 0><<<gFin, 256, 0, stream>>>(H2f, H2b, nullptr, nullptr,
        wfin_h, wfin_l, wfin_h + 256, wfin_l + 256, 1024,
        Yf, nullptr, Yb, nullptr, nullptr, nullptr, n, 128);
    // A2: out = dinv_f*agg_f(yf) + dinv_b*agg_b(yb) + cvec
    k_agg2<<<ab, 256, 0, stream>>>(Yf, Yb,
        off_f, lst_f, off_b, lst_b, dinv_f, dinv_b, cvec, out, n);
}

// Round 11
// 292.058 us; speedup vs baseline: 2.1690x; 1.1561x over previous
//
#include <hip/hip_runtime.h>

typedef unsigned int   u32;
typedef unsigned short u16;
typedef __attribute__((ext_vector_type(8))) short bf16x8;
typedef __attribute__((ext_vector_type(4))) float f32x4;

// ---------- bf16 helpers ----------
__device__ __forceinline__ u16 f2bf(float f) {
    u32 u = __float_as_uint(f);
    u32 r = u + 0x7fffu + ((u >> 16) & 1u);
    return (u16)(r >> 16);
}
__device__ __forceinline__ float bf2f(u16 h) {
    return __uint_as_float(((u32)h) << 16);
}
__device__ __forceinline__ float lof(u32 q) { return __uint_as_float(q << 16); }
__device__ __forceinline__ float hif(u32 q) { return __uint_as_float(q & 0xffff0000u); }
__device__ __forceinline__ u32 pk(float a, float b) {
    return (u32)f2bf(a) | ((u32)f2bf(b) << 16);
}
__device__ __forceinline__ void gl_lds16(const void* g, void* l) {
    __builtin_amdgcn_global_load_lds(
        (const __attribute__((address_space(1))) u32*)g,
        (__attribute__((address_space(3))) u32*)l, 16, 0, 0);
}
__device__ __forceinline__ void st16(void* dst, const u16* h) {
    uint4 q;
    q.x = (u32)h[0] | ((u32)h[1] << 16);
    q.y = (u32)h[2] | ((u32)h[3] << 16);
    q.z = (u32)h[4] | ((u32)h[5] << 16);
    q.w = (u32)h[6] | ((u32)h[7] << 16);
    *(uint4*)dst = q;
}

// ---------------- degree count ----------------
__global__ __launch_bounds__(256)
void k_deg(const int* __restrict__ src, const int* __restrict__ dst,
           int* __restrict__ deg_f, int* __restrict__ deg_b, int E) {
    int e = blockIdx.x * 256 + threadIdx.x;
    if (e < E) {
        atomicAdd(&deg_f[dst[e]], 1);
        atomicAdd(&deg_b[src[e]], 1);
    }
}

// ---------------- hierarchical scan, stage 1: per-block sums + dinv ----------------
// grid = 2*nblk (fwd blocks then bwd blocks), 256 threads.
__global__ __launch_bounds__(256)
void k_scan1(const int* __restrict__ deg_f, const int* __restrict__ deg_b,
             float* __restrict__ dinv_f, float* __restrict__ dinv_b,
             int* __restrict__ bsum, int n, int nblk) {
    __shared__ int red[4];
    int dir = blockIdx.x >= nblk;
    int b = dir ? blockIdx.x - nblk : blockIdx.x;
    const int* deg = dir ? deg_b : deg_f;
    float* dinv = dir ? dinv_b : dinv_f;
    int idx = b * 256 + threadIdx.x;
    int d = 0;
    if (idx < n) {
        d = deg[idx];
        dinv[idx] = rsqrtf((float)(d + 1));
    }
    int s = d;
    s += __shfl_down(s, 32);
    s += __shfl_down(s, 16);
    s += __shfl_down(s, 8);
    s += __shfl_down(s, 4);
    s += __shfl_down(s, 2);
    s += __shfl_down(s, 1);
    int wv = threadIdx.x >> 6;
    if ((threadIdx.x & 63) == 0) red[wv] = s;
    __syncthreads();
    if (threadIdx.x == 0)
        bsum[blockIdx.x] = red[0] + red[1] + red[2] + red[3];
}

// ---------------- stage 2: segmented exclusive scan of block sums ----------------
// 1 block, 256 threads. fwd sums in lanes 0..127, bwd in 128..255 (nblk <= 128).
__global__ __launch_bounds__(256)
void k_scan2(const int* __restrict__ bsum, int* __restrict__ bpre, int nblk) {
    __shared__ int sm[256];
    int t = threadIdx.x;
    int seg = t >> 7;
    int i = t & 127;
    int val = (i < nblk) ? bsum[seg * nblk + i] : 0;
    sm[t] = val;
    __syncthreads();
    for (int s = 1; s < 128; s <<= 1) {
        int v = ((t & 127) >= s) ? sm[t - s] : 0;
        __syncthreads();
        sm[t] += v;
        __syncthreads();
    }
    if (i < nblk) bpre[seg * nblk + i] = sm[t] - val;
}

// ---------------- stage 3: local scan + block offset -> off/cur ----------------
__global__ __launch_bounds__(256)
void k_scan3(const int* __restrict__ deg_f, const int* __restrict__ deg_b,
             const int* __restrict__ bpre,
             int* __restrict__ off_f, int* __restrict__ cur_f,
             int* __restrict__ off_b, int* __restrict__ cur_b,
             int n, int nblk, int E) {
    __shared__ int sm[256];
    int dir = blockIdx.x >= nblk;
    int b = dir ? blockIdx.x - nblk : blockIdx.x;
    const int* deg = dir ? deg_b : deg_f;
    int* off = dir ? off_b : off_f;
    int* cur = dir ? cur_b : cur_f;
    int base = bpre[blockIdx.x];
    int idx = b * 256 + threadIdx.x;
    int d = (idx < n) ? deg[idx] : 0;
    sm[threadIdx.x] = d;
    __syncthreads();
    for (int s = 1; s < 256; s <<= 1) {
        int v = (threadIdx.x >= s) ? sm[threadIdx.x - s] : 0;
        __syncthreads();
        sm[threadIdx.x] += v;
        __syncthreads();
    }
    if (idx < n) {
        int excl = base + sm[threadIdx.x] - d;
        off[idx] = excl;
        cur[idx] = excl;
    }
    if (blockIdx.x == 0 && threadIdx.x == 0) {
        off_f[n] = E;      // total degree per direction == E
        off_b[n] = E;
    }
}

// ---------------- CSR fill ----------------
__global__ __launch_bounds__(256)
void k_fill(const int* __restrict__ src, const int* __restrict__ dst,
            int* __restrict__ cur_f, int* __restrict__ cur_b,
            int* __restrict__ lst_f, int* __restrict__ lst_b, int E) {
    int e = blockIdx.x * 256 + threadIdx.x;
    if (e < E) {
        int s = src[e], d = dst[e];
        int pf = atomicAdd(&cur_f[d], 1);
        lst_f[pf] = s;
        int pb = atomicAdd(&cur_b[s], 1);
        lst_b[pb] = d;
    }
}

// ---------------- all 5 weight transposes + hi/lo split in one launch ----------------
__global__ __launch_bounds__(256)
void k_wsplit5(const float* __restrict__ W0, const float* __restrict__ W1,
               const float* __restrict__ W2, const float* __restrict__ W3,
               const float* __restrict__ W4,
               u16* __restrict__ h0, u16* __restrict__ l0,
               u16* __restrict__ h1, u16* __restrict__ l1,
               u16* __restrict__ h2, u16* __restrict__ l2,
               u16* __restrict__ h3, u16* __restrict__ l3,
               u16* __restrict__ h4, u16* __restrict__ l4)
{
    int which = blockIdx.x >> 8;
    int sub = ((blockIdx.x & 255) << 8) | threadIdx.x;   // 0..65535
    const float* W; u16 *H, *L; int kshift, N;
    switch (which) {
        case 0: W = W0; H = h0; L = l0; kshift = 8; N = 256; break;
        case 1: W = W1; H = h1; L = l1; kshift = 8; N = 256; break;
        case 2: W = W2; H = h2; L = l2; kshift = 8; N = 256; break;
        case 3: W = W3; H = h3; L = l3; kshift = 8; N = 256; break;
        default: W = W4; H = h4; L = l4; kshift = 9; N = 128; break;
    }
    int ni = sub >> kshift;
    int ki = sub & ((1 << kshift) - 1);
    float v = W[(size_t)ki * N + ni];
    u16 hh = f2bf(v);
    H[sub] = hh;
    L[sub] = f2bf(v - bf2f(hh));
}

// ---------------- cvec = bfin + bf2^T Wfin[0:256] + bb2^T Wfin[256:512] ----------------
__global__ __launch_bounds__(256)
void k_cvec(const float* __restrict__ bfin, const float* __restrict__ bf2,
            const float* __restrict__ bb2, const float* __restrict__ Wfin,
            float* __restrict__ cvec) {
    __shared__ float red[256];
    int j = blockIdx.x;        // 0..127
    int t = threadIdx.x;       // 0..255
    float s = bf2[t] * Wfin[(size_t)t * 128 + j]
            + bb2[t] * Wfin[(size_t)(t + 256) * 128 + j];
    red[t] = s;
    __syncthreads();
    for (int st = 128; st > 0; st >>= 1) {
        if (t < st) red[t] += red[t + st];
        __syncthreads();
    }
    if (t == 0) cvec[j] = red[0] + bfin[j];
}

// ---------------- MFMA GEMM (fwd+bwd merged via blockIdx.z) ----------------
// C[M,N] = A[M,256] @ Bt[N,256]^T ; tile 128x128, BK=32, 4 waves (2x2).
// AMODE 0: A = bf16 hi plane [M][256] (gload_lds);  AMODE 1: A = f32 (reg split).
// PASS3: include al*bh pass (needs A lo plane).  WLO: write C lo plane.
template<int AMODE, int PASS3, int WLO>
__global__ __launch_bounds__(256)
void k_gemm2(const void* __restrict__ A0, const void* __restrict__ A1p,
             const u16* __restrict__ Alo0, const u16* __restrict__ Alo1,
             const u16* __restrict__ Bhi0, const u16* __restrict__ Blo0,
             const u16* __restrict__ Bhi1, const u16* __restrict__ Blo1, int ldb,
             u16* __restrict__ Chi0, u16* __restrict__ Clo0,
             u16* __restrict__ Chi1, u16* __restrict__ Clo1,
             const float* __restrict__ rs0, const float* __restrict__ rs1,
             int M, int N)
{
    constexpr int ALO = 8192;
    constexpr int BHI = PASS3 ? 16384 : 8192;
    constexpr int BLO = BHI + 8192;
    __shared__ char smem[PASS3 ? 32768 : 24576];

    const int z = blockIdx.z;
    const void* Aptr = z ? A1p : A0;
    const u16* Alo   = z ? Alo1 : Alo0;
    const u16* Bhi   = z ? Bhi1 : Bhi0;
    const u16* Blo   = z ? Blo1 : Blo0;
    u16* Chi         = z ? Chi1 : Chi0;
    u16* Clo         = z ? Clo1 : Clo0;
    const float* rowscale = z ? rs1 : rs0;

    const int tid  = threadIdx.x;
    const int lane = tid & 63;
    const int wid  = tid >> 6;
    const int wm   = wid >> 1, wn = wid & 1;
    const int bm   = blockIdx.x * 128;
    const int bn   = blockIdx.y * 128;

    f32x4 acc[4][4];
#pragma unroll
    for (int i = 0; i < 4; ++i)
#pragma unroll
        for (int j = 0; j < 4; ++j) acc[i][j] = (f32x4){0.f, 0.f, 0.f, 0.f};

    const int gsw  = ((lane >> 2) & 3) ^ ((lane >> 4) & 3);
    const int gsta = ((lane & 3) ^ gsw) << 4;
    const int sl   = (lane & 3) ^ ((lane >> 2) & 3);
    const int hi4  = lane >> 4;
    const int gsel = ((hi4 ^ sl) << 4);
    const int frow = lane & 15;

    for (int k0 = 0; k0 < 256; k0 += 32) {
        if (k0) __syncthreads();

#pragma unroll
        for (int p = 0; p < 2; ++p) {
            int c   = p * 4 + wid;
            int row = c * 16 + (lane >> 2);
            size_t rb = (size_t)(bn + row) * ldb + (size_t)k0 * 2 + gsta;
            gl_lds16((const char*)Bhi + rb, smem + BHI + c * 1024);
            gl_lds16((const char*)Blo + rb, smem + BLO + c * 1024);
        }
        if (AMODE == 0) {
            const u16* Ah = (const u16*)Aptr;
#pragma unroll
            for (int p = 0; p < 2; ++p) {
                int c   = p * 4 + wid;
                int row = c * 16 + (lane >> 2);
                int grow = bm + row; if (grow >= M) grow = M - 1;
                size_t rb = (size_t)grow * 512 + (size_t)k0 * 2 + gsta;
                gl_lds16((const char*)Ah + rb, smem + c * 1024);
                if (PASS3)
                    gl_lds16((const char*)Alo + rb, smem + ALO + c * 1024);
            }
        } else {
            const float* Af = (const float*)Aptr;
            int row  = tid >> 1;
            int half = tid & 1;
            int grow = bm + row; if (grow >= M) grow = M - 1;
            const float* srcp = Af + (size_t)grow * 256 + k0 + half * 16;
            float vv[16];
            *(float4*)(vv + 0)  = *(const float4*)(srcp + 0);
            *(float4*)(vv + 4)  = *(const float4*)(srcp + 4);
            *(float4*)(vv + 8)  = *(const float4*)(srcp + 8);
            *(float4*)(vv + 12) = *(const float4*)(srcp + 12);
            u16 h[16], l[16];
#pragma unroll
            for (int i = 0; i < 16; ++i) {
                h[i] = f2bf(vv[i]);
                l[i] = f2bf(vv[i] - bf2f(h[i]));
            }
            int swz = (row & 3) ^ ((row >> 2) & 3);
            char* dh = smem + row * 64;
            st16(dh + (((half * 2 + 0) ^ swz) << 4), h + 0);
            st16(dh + (((half * 2 + 1) ^ swz) << 4), h + 8);
            if (PASS3) {
                char* dl = smem + ALO + row * 64;
                st16(dl + (((half * 2 + 0) ^ swz) << 4), l + 0);
                st16(dl + (((half * 2 + 1) ^ swz) << 4), l + 8);
            }
        }
        __syncthreads();

        bf16x8 ah[4], al[4], bh[4], bl[4];
#pragma unroll
        for (int fm = 0; fm < 4; ++fm) {
            int r = wm * 64 + fm * 16 + frow;
            ah[fm] = *(const bf16x8*)(smem + r * 64 + gsel);
            if (PASS3) al[fm] = *(const bf16x8*)(smem + ALO + r * 64 + gsel);
        }
#pragma unroll
        for (int fn = 0; fn < 4; ++fn) {
            int r = wn * 64 + fn * 16 + frow;
            bh[fn] = *(const bf16x8*)(smem + BHI + r * 64 + gsel);
            bl[fn] = *(const bf16x8*)(smem + BLO + r * 64 + gsel);
        }
#pragma unroll
        for (int fm = 0; fm < 4; ++fm)
#pragma unroll
            for (int fn = 0; fn < 4; ++fn)
                acc[fm][fn] = __builtin_amdgcn_mfma_f32_16x16x32_bf16(ah[fm], bh[fn], acc[fm][fn], 0, 0, 0);
#pragma unroll
        for (int fm = 0; fm < 4; ++fm)
#pragma unroll
            for (int fn = 0; fn < 4; ++fn)
                acc[fm][fn] = __builtin_amdgcn_mfma_f32_16x16x32_bf16(ah[fm], bl[fn], acc[fm][fn], 0, 0, 0);
        if (PASS3) {
#pragma unroll
            for (int fm = 0; fm < 4; ++fm)
#pragma unroll
                for (int fn = 0; fn < 4; ++fn)
                    acc[fm][fn] = __builtin_amdgcn_mfma_f32_16x16x32_bf16(al[fm], bh[fn], acc[fm][fn], 0, 0, 0);
        }
    }

#pragma unroll
    for (int fm = 0; fm < 4; ++fm) {
#pragma unroll
        for (int q = 0; q < 4; ++q) {
            int row = bm + wm * 64 + fm * 16 + hi4 * 4 + q;
            if (row < M) {
                float s = rowscale ? rowscale[row] : 1.0f;
#pragma unroll
                for (int fn = 0; fn < 4; ++fn) {
                    int col = bn + wn * 64 + fn * 16 + frow;
                    float v = acc[fm][fn][q] * s;
                    u16 hb = f2bf(v);
                    Chi[(size_t)row * N + col] = hb;
                    if (WLO) Clo[(size_t)row * N + col] = f2bf(v - bf2f(hb));
                }
            }
        }
    }
}

// ---------------- layer-1 aggregation: 2 nodes/wave, hi-only output ----------------
__global__ __launch_bounds__(256)
void k_agg1(const u16* __restrict__ ghf, const u16* __restrict__ glf,
            const u16* __restrict__ ghb, const u16* __restrict__ glb,
            const int* __restrict__ off_f, const int* __restrict__ lst_f,
            const int* __restrict__ off_b, const int* __restrict__ lst_b,
            const float* __restrict__ dinv_f, const float* __restrict__ dinv_b,
            const float* __restrict__ b_f, const float* __restrict__ b_b,
            u16* __restrict__ ozf, u16* __restrict__ ozb, int n)
{
    int nb = gridDim.x >> 1;
    int stack = blockIdx.x >= nb;
    int bx = stack ? (blockIdx.x - nb) : blockIdx.x;
    const u16* gh = stack ? ghb : ghf;
    const u16* gl = stack ? glb : glf;
    const int* off = stack ? off_b : off_f;
    const int* lst = stack ? lst_b : lst_f;
    const float* dinv = stack ? dinv_b : dinv_f;
    const float* bias = stack ? b_b : b_f;
    u16* oz = stack ? ozb : ozf;

    int wv = threadIdx.x >> 6;
    int half = (threadIdx.x >> 5) & 1;
    int l = threadIdx.x & 31;
    int v = bx * 8 + wv * 2 + half;
    if (v >= n) return;
    int f0 = l * 8;                        // 8 features, 16 B per lane

    uint4 qh = *(const uint4*)(gh + (size_t)v * 256 + f0);
    uint4 ql = *(const uint4*)(gl + (size_t)v * 256 + f0);
    float a0 = lof(qh.x) + lof(ql.x), a1 = hif(qh.x) + hif(ql.x);
    float a2 = lof(qh.y) + lof(ql.y), a3 = hif(qh.y) + hif(ql.y);
    float a4 = lof(qh.z) + lof(ql.z), a5 = hif(qh.z) + hif(ql.z);
    float a6 = lof(qh.w) + lof(ql.w), a7 = hif(qh.w) + hif(ql.w);

    int s0 = off[v], s1 = off[v + 1];
    int j = s0;
    for (; j + 4 <= s1; j += 4) {
        int u0 = lst[j], u1 = lst[j + 1], u2 = lst[j + 2], u3 = lst[j + 3];
        uint4 m0 = *(const uint4*)(gh + (size_t)u0 * 256 + f0);
        uint4 m1 = *(const uint4*)(gh + (size_t)u1 * 256 + f0);
        uint4 m2 = *(const uint4*)(gh + (size_t)u2 * 256 + f0);
        uint4 m3 = *(const uint4*)(gh + (size_t)u3 * 256 + f0);
        a0 += lof(m0.x) + lof(m1.x) + lof(m2.x) + lof(m3.x);
        a1 += hif(m0.x) + hif(m1.x) + hif(m2.x) + hif(m3.x);
        a2 += lof(m0.y) + lof(m1.y) + lof(m2.y) + lof(m3.y);
        a3 += hif(m0.y) + hif(m1.y) + hif(m2.y) + hif(m3.y);
        a4 += lof(m0.z) + lof(m1.z) + lof(m2.z) + lof(m3.z);
        a5 += hif(m0.z) + hif(m1.z) + hif(m2.z) + hif(m3.z);
        a6 += lof(m0.w) + lof(m1.w) + lof(m2.w) + lof(m3.w);
        a7 += hif(m0.w) + hif(m1.w) + hif(m2.w) + hif(m3.w);
    }
    for (; j < s1; ++j) {
        int u = lst[j];
        uint4 m = *(const uint4*)(gh + (size_t)u * 256 + f0);
        a0 += lof(m.x); a1 += hif(m.x);
        a2 += lof(m.y); a3 += hif(m.y);
        a4 += lof(m.z); a5 += hif(m.z);
        a6 += lof(m.w); a7 += hif(m.w);
    }
    float sc = dinv[v];
    float4 bA = *(const float4*)(bias + f0);
    float4 bB = *(const float4*)(bias + f0 + 4);
    float o0 = fmaxf(a0 * sc + bA.x, 0.f), o1 = fmaxf(a1 * sc + bA.y, 0.f);
    float o2 = fmaxf(a2 * sc + bA.z, 0.f), o3 = fmaxf(a3 * sc + bA.w, 0.f);
    float o4 = fmaxf(a4 * sc + bB.x, 0.f), o5 = fmaxf(a5 * sc + bB.y, 0.f);
    float o6 = fmaxf(a6 * sc + bB.z, 0.f), o7 = fmaxf(a7 * sc + bB.w, 0.f);
    uint4 r;
    r.x = pk(o0, o1); r.y = pk(o2, o3); r.z = pk(o4, o5); r.w = pk(o6, o7);
    *(uint4*)(oz + (size_t)v * 256 + f0) = r;
}

// ---------------- final aggregation: dir-split lanes, hi-only Y -> f32 out ----------------
__global__ __launch_bounds__(256)
void k_agg2(const u16* __restrict__ yf, const u16* __restrict__ yb,
            const int* __restrict__ off_f, const int* __restrict__ lst_f,
            const int* __restrict__ off_b, const int* __restrict__ lst_b,
            const float* __restrict__ dinv_f, const float* __restrict__ dinv_b,
            const float* __restrict__ cvec, float* __restrict__ out, int n)
{
    int wv = threadIdx.x >> 6, lane = threadIdx.x & 63;
    int v = blockIdx.x * 4 + wv;
    if (v >= n) return;
    int dirb = lane >> 5;                  // 0: fwd lanes, 1: bwd lanes
    int l = lane & 31;
    int f0 = l * 4;                        // 4 features, 8 B per lane

    const u16* y   = dirb ? yb : yf;
    const int* off = dirb ? off_b : off_f;
    const int* lst = dirb ? lst_b : lst_f;
    float dv = dirb ? dinv_b[v] : dinv_f[v];

    uint2 q = *(const uint2*)(y + (size_t)v * 128 + f0);
    float a0 = lof(q.x), a1 = hif(q.x), a2 = lof(q.y), a3 = hif(q.y);

    int s0 = off[v], s1 = off[v + 1];
    int j = s0;
    for (; j + 4 <= s1; j += 4) {
        int u0 = lst[j], u1 = lst[j + 1], u2 = lst[j + 2], u3 = lst[j + 3];
        uint2 m0 = *(const uint2*)(y + (size_t)u0 * 128 + f0);
        uint2 m1 = *(const uint2*)(y + (size_t)u1 * 128 + f0);
        uint2 m2 = *(const uint2*)(y + (size_t)u2 * 128 + f0);
        uint2 m3 = *(const uint2*)(y + (size_t)u3 * 128 + f0);
        a0 += lof(m0.x) + lof(m1.x) + lof(m2.x) + lof(m3.x);
        a1 += hif(m0.x) + hif(m1.x) + hif(m2.x) + hif(m3.x);
        a2 += lof(m0.y) + lof(m1.y) + lof(m2.y) + lof(m3.y);
        a3 += hif(m0.y) + hif(m1.y) + hif(m2.y) + hif(m3.y);
    }
    for (; j < s1; ++j) {
        int u = lst[j];
        uint2 m = *(const uint2*)(y + (size_t)u * 128 + f0);
        a0 += lof(m.x); a1 += hif(m.x);
        a2 += lof(m.y); a3 += hif(m.y);
    }
    float o0 = a0 * dv, o1 = a1 * dv, o2 = a2 * dv, o3 = a3 * dv;
    o0 += __shfl_xor(o0, 32);
    o1 += __shfl_xor(o1, 32);
    o2 += __shfl_xor(o2, 32);
    o3 += __shfl_xor(o3, 32);
    if (dirb == 0) {
        float4 c4 = *(const float4*)(cvec + f0);
        float4 o;
        o.x = o0 + c4.x; o.y = o1 + c4.y; o.z = o2 + c4.z; o.w = o3 + c4.w;
        *(float4*)(out + (size_t)v * 128 + f0) = o;
    }
}

extern "C" void kernel_launch(void* const* d_in, const int* in_sizes, int n_in,
                              void* d_out, int out_size, void* d_ws, size_t ws_size,
                              hipStream_t stream) {
    const float* x    = (const float*)d_in[0];
    const int*   ei   = (const int*)d_in[1];
    const float* Wf1  = (const float*)d_in[2];
    const float* bf1  = (const float*)d_in[3];
    const float* Wf2  = (const float*)d_in[4];
    const float* bf2  = (const float*)d_in[5];
    const float* Wb1  = (const float*)d_in[6];
    const float* bb1  = (const float*)d_in[7];
    const float* Wb2  = (const float*)d_in[8];
    const float* bb2  = (const float*)d_in[9];
    const float* Wfin = (const float*)d_in[10];
    const float* bfin = (const float*)d_in[11];
    float* out = (float*)d_out;

    const int n = in_sizes[0] / 256;   // 20000
    const int E = in_sizes[1] / 2;     // 320000
    const int* src = ei;
    const int* dst = ei + E;

    char* p = (char*)d_ws;
    auto take = [&](size_t bytes) -> void* {
        void* q = (void*)p;
        p += (bytes + 255) & ~(size_t)255;
        return q;
    };
    // activation planes
    u16* P1f_h = (u16*)take((size_t)n * 256 * 2);
    u16* P1f_l = (u16*)take((size_t)n * 256 * 2);
    u16* P1b_h = (u16*)take((size_t)n * 256 * 2);
    u16* P1b_l = (u16*)take((size_t)n * 256 * 2);
    u16* Zf    = (u16*)take((size_t)n * 256 * 2);
    u16* Zb    = (u16*)take((size_t)n * 256 * 2);
    u16* H2f   = (u16*)take((size_t)n * 256 * 2);
    u16* H2b   = (u16*)take((size_t)n * 256 * 2);
    u16* Yf    = (u16*)take((size_t)n * 128 * 2);
    u16* Yb    = (u16*)take((size_t)n * 128 * 2);
    // weight planes
    u16* w1f_h = (u16*)take(65536 * 2); u16* w1f_l = (u16*)take(65536 * 2);
    u16* w2f_h = (u16*)take(65536 * 2); u16* w2f_l = (u16*)take(65536 * 2);
    u16* w1b_h = (u16*)take(65536 * 2); u16* w1b_l = (u16*)take(65536 * 2);
    u16* w2b_h = (u16*)take(65536 * 2); u16* w2b_l = (u16*)take(65536 * 2);
    u16* wfin_h = (u16*)take(65536 * 2); u16* wfin_l = (u16*)take(65536 * 2);
    float* cvec = (float*)take(128 * sizeof(float));
    // CSR
    int*   deg_f  = (int*)take((size_t)n * sizeof(int));
    int*   deg_b  = (int*)take((size_t)n * sizeof(int));
    int*   off_f  = (int*)take((size_t)(n + 1) * sizeof(int));
    int*   off_b  = (int*)take((size_t)(n + 1) * sizeof(int));
    int*   cur_f  = (int*)take((size_t)n * sizeof(int));
    int*   cur_b  = (int*)take((size_t)n * sizeof(int));
    int*   lst_f  = (int*)take((size_t)E * sizeof(int));
    int*   lst_b  = (int*)take((size_t)E * sizeof(int));
    float* dinv_f = (float*)take((size_t)n * sizeof(float));
    float* dinv_b = (float*)take((size_t)n * sizeof(float));
    int*   bsum   = (int*)take(256 * sizeof(int));
    int*   bpre   = (int*)take(256 * sizeof(int));

    hipMemsetAsync(deg_f, 0, (size_t)n * sizeof(int), stream);
    hipMemsetAsync(deg_b, 0, (size_t)n * sizeof(int), stream);

    const int nblk = (n + 255) / 256;     // 79  (<= 128 required by k_scan2)
    int eb = (E + 255) / 256;
    k_deg<<<eb, 256, 0, stream>>>(src, dst, deg_f, deg_b, E);
    k_scan1<<<2 * nblk, 256, 0, stream>>>(deg_f, deg_b, dinv_f, dinv_b, bsum, n, nblk);
    k_scan2<<<1, 256, 0, stream>>>(bsum, bpre, nblk);
    k_scan3<<<2 * nblk, 256, 0, stream>>>(deg_f, deg_b, bpre,
        off_f, cur_f, off_b, cur_b, n, nblk, E);
    k_fill<<<eb, 256, 0, stream>>>(src, dst, cur_f, cur_b, lst_f, lst_b, E);
    k_wsplit5<<<1280, 256, 0, stream>>>(Wf1, Wf2, Wb1, Wb2, Wfin,
        w1f_h, w1f_l, w2f_h, w2f_l, w1b_h, w1b_l, w2b_h, w2b_l, wfin_h, wfin_l);
    k_cvec<<<128, 256, 0, stream>>>(bfin, bf2, bb2, Wfin, cvec);

    const int gx = (n + 127) / 128;       // 157
    dim3 gBig(gx, 2, 2);                  // N=256, fwd+bwd
    dim3 gFin(gx, 1, 2);                  // N=128, fwd+bwd
    int ab = (n + 3) / 4;
    int a1b = 2 * ((n + 7) / 8);

    // G1: h1 = (x @ W1) * dinv   (3-pass, hi+lo out)
    k_gemm2<1, 1, 1><<<gBig, 256, 0, stream>>>(x, x, nullptr, nullptr,
        w1f_h, w1f_l, w1b_h, w1b_l, 512,
        P1f_h, P1f_l, P1b_h, P1b_l, dinv_f, dinv_b, n, 256);
    // A1: z1 = relu(dinv * agg(h1) + b1)   (hi-only out)
    k_agg1<<<a1b, 256, 0, stream>>>(P1f_h, P1f_l, P1b_h, P1b_l,
        off_f, lst_f, off_b, lst_b, dinv_f, dinv_b, bf1, bb1, Zf, Zb, n);
    // G2: h2 = (z1 @ W2) * dinv   (2-pass, hi-only out)
    k_gemm2<0, 0, 0><<<gBig, 256, 0, stream>>>(Zf, Zb, nullptr, nullptr,
        w2f_h, w2f_l, w2b_h, w2b_l, 512,
        H2f, nullptr, H2b, nullptr, dinv_f, dinv_b, n, 256);
    // Gfin: y = h2 @ Wfin_half    (2-pass, hi-only out, no rowscale)
    k_gemm2<0, 0, 0><<<gFin, 256, 0, stream>>>(H2f, H2b, nullptr, nullptr,
        wfin_h, wfin_l, wfin_h + 256, wfin_l + 256, 1024,
        Yf, nullptr, Yb, nullptr, nullptr, nullptr, n, 128);
    // A2: out = dinv_f*agg_f(yf) + dinv_b*agg_b(yb) + cvec
    k_agg2<<<ab, 256, 0, stream>>>(Yf, Yb,
        off_f, lst_f, off_b, lst_b, dinv_f, dinv_b, cvec, out, n);
}

// Round 13
// 279.919 us; speedup vs baseline: 2.2630x; 1.0434x over previous
//
#include <hip/hip_runtime.h>

typedef unsigned int   u32;
typedef unsigned short u16;
typedef __attribute__((ext_vector_type(8))) short bf16x8;
typedef __attribute__((ext_vector_type(4))) float f32x4;

// ---------- bf16 helpers ----------
__device__ __forceinline__ u16 f2bf(float f) {
    u32 u = __float_as_uint(f);
    u32 r = u + 0x7fffu + ((u >> 16) & 1u);
    return (u16)(r >> 16);
}
__device__ __forceinline__ float bf2f(u16 h) {
    return __uint_as_float(((u32)h) << 16);
}
__device__ __forceinline__ float lof(u32 q) { return __uint_as_float(q << 16); }
__device__ __forceinline__ float hif(u32 q) { return __uint_as_float(q & 0xffff0000u); }
__device__ __forceinline__ u32 pk(float a, float b) {
    return (u32)f2bf(a) | ((u32)f2bf(b) << 16);
}
__device__ __forceinline__ void gl_lds16(const void* g, void* l) {
    __builtin_amdgcn_global_load_lds(
        (const __attribute__((address_space(1))) u32*)g,
        (__attribute__((address_space(3))) u32*)l, 16, 0, 0);
}

// ---------------- degree count ----------------
__global__ __launch_bounds__(256)
void k_deg(const int* __restrict__ src, const int* __restrict__ dst,
           int* __restrict__ deg_f, int* __restrict__ deg_b, int E) {
    int e = blockIdx.x * 256 + threadIdx.x;
    if (e < E) {
        atomicAdd(&deg_f[dst[e]], 1);
        atomicAdd(&deg_b[src[e]], 1);
    }
}

// ---------------- hierarchical scan, stage 1: per-block sums + dinv ----------------
__global__ __launch_bounds__(256)
void k_scan1(const int* __restrict__ deg_f, const int* __restrict__ deg_b,
             float* __restrict__ dinv_f, float* __restrict__ dinv_b,
             int* __restrict__ bsum, int n, int nblk) {
    __shared__ int red[4];
    int dir = blockIdx.x >= nblk;
    int b = dir ? blockIdx.x - nblk : blockIdx.x;
    const int* deg = dir ? deg_b : deg_f;
    float* dinv = dir ? dinv_b : dinv_f;
    int idx = b * 256 + threadIdx.x;
    int d = 0;
    if (idx < n) {
        d = deg[idx];
        dinv[idx] = rsqrtf((float)(d + 1));
    }
    int s = d;
    s += __shfl_down(s, 32);
    s += __shfl_down(s, 16);
    s += __shfl_down(s, 8);
    s += __shfl_down(s, 4);
    s += __shfl_down(s, 2);
    s += __shfl_down(s, 1);
    int wv = threadIdx.x >> 6;
    if ((threadIdx.x & 63) == 0) red[wv] = s;
    __syncthreads();
    if (threadIdx.x == 0)
        bsum[blockIdx.x] = red[0] + red[1] + red[2] + red[3];
}

// ---------------- stage 2: segmented exclusive scan of block sums ----------------
__global__ __launch_bounds__(256)
void k_scan2(const int* __restrict__ bsum, int* __restrict__ bpre, int nblk) {
    __shared__ int sm[256];
    int t = threadIdx.x;
    int seg = t >> 7;
    int i = t & 127;
    int val = (i < nblk) ? bsum[seg * nblk + i] : 0;
    sm[t] = val;
    __syncthreads();
    for (int s = 1; s < 128; s <<= 1) {
        int v = ((t & 127) >= s) ? sm[t - s] : 0;
        __syncthreads();
        sm[t] += v;
        __syncthreads();
    }
    if (i < nblk) bpre[seg * nblk + i] = sm[t] - val;
}

// ---------------- stage 3: local scan + block offset -> off/cur ----------------
__global__ __launch_bounds__(256)
void k_scan3(const int* __restrict__ deg_f, const int* __restrict__ deg_b,
             const int* __restrict__ bpre,
             int* __restrict__ off_f, int* __restrict__ cur_f,
             int* __restrict__ off_b, int* __restrict__ cur_b,
             int n, int nblk, int E) {
    __shared__ int sm[256];
    int dir = blockIdx.x >= nblk;
    int b = dir ? blockIdx.x - nblk : blockIdx.x;
    const int* deg = dir ? deg_b : deg_f;
    int* off = dir ? off_b : off_f;
    int* cur = dir ? cur_b : cur_f;
    int base = bpre[blockIdx.x];
    int idx = b * 256 + threadIdx.x;
    int d = (idx < n) ? deg[idx] : 0;
    sm[threadIdx.x] = d;
    __syncthreads();
    for (int s = 1; s < 256; s <<= 1) {
        int v = (threadIdx.x >= s) ? sm[threadIdx.x - s] : 0;
        __syncthreads();
        sm[threadIdx.x] += v;
        __syncthreads();
    }
    if (idx < n) {
        int excl = base + sm[threadIdx.x] - d;
        off[idx] = excl;
        cur[idx] = excl;
    }
    if (blockIdx.x == 0 && threadIdx.x == 0) {
        off_f[n] = E;
        off_b[n] = E;
    }
}

// ---------------- CSR fill ----------------
__global__ __launch_bounds__(256)
void k_fill(const int* __restrict__ src, const int* __restrict__ dst,
            int* __restrict__ cur_f, int* __restrict__ cur_b,
            int* __restrict__ lst_f, int* __restrict__ lst_b, int E) {
    int e = blockIdx.x * 256 + threadIdx.x;
    if (e < E) {
        int s = src[e], d = dst[e];
        int pf = atomicAdd(&cur_f[d], 1);
        lst_f[pf] = s;
        int pb = atomicAdd(&cur_b[s], 1);
        lst_b[pb] = d;
    }
}

// ---------------- fused prep: 5 weight splits + cvec + x hi-split ----------------
// blocks [0,1280): weight transpose+split (256 blocks each)
// blocks [1280,1408): cvec column j = blockIdx-1280
// blocks [1408, ...): x -> bf16 hi plane, 1024 elems/block
__global__ __launch_bounds__(256)
void k_prep(const float* __restrict__ W0, const float* __restrict__ W1,
            const float* __restrict__ W2, const float* __restrict__ W3,
            const float* __restrict__ W4,
            u16* __restrict__ h0, u16* __restrict__ l0,
            u16* __restrict__ h1, u16* __restrict__ l1,
            u16* __restrict__ h2, u16* __restrict__ l2,
            u16* __restrict__ h3, u16* __restrict__ l3,
            u16* __restrict__ h4, u16* __restrict__ l4,
            const float* __restrict__ bfin, const float* __restrict__ bf2,
            const float* __restrict__ bb2, float* __restrict__ cvec,
            const float* __restrict__ x, u16* __restrict__ xh, int xcount)
{
    __shared__ float red[256];
    int b = blockIdx.x;
    int t = threadIdx.x;
    if (b < 1280) {
        int which = b >> 8;
        int sub = ((b & 255) << 8) | t;
        const float* W; u16 *H, *L; int kshift, N;
        switch (which) {
            case 0: W = W0; H = h0; L = l0; kshift = 8; N = 256; break;
            case 1: W = W1; H = h1; L = l1; kshift = 8; N = 256; break;
            case 2: W = W2; H = h2; L = l2; kshift = 8; N = 256; break;
            case 3: W = W3; H = h3; L = l3; kshift = 8; N = 256; break;
            default: W = W4; H = h4; L = l4; kshift = 9; N = 128; break;
        }
        int ni = sub >> kshift;
        int ki = sub & ((1 << kshift) - 1);
        float v = W[(size_t)ki * N + ni];
        u16 hh = f2bf(v);
        H[sub] = hh;
        L[sub] = f2bf(v - bf2f(hh));
    } else if (b < 1408) {
        int j = b - 1280;   // 0..127
        float s = bf2[t] * W4[(size_t)t * 128 + j]
                + bb2[t] * W4[(size_t)(t + 256) * 128 + j];
        red[t] = s;
        __syncthreads();
        for (int st = 128; st > 0; st >>= 1) {
            if (t < st) red[t] += red[t + st];
            __syncthreads();
        }
        if (t == 0) cvec[j] = red[0] + bfin[j];
    } else {
        int i = (b - 1408) * 1024 + t * 4;
        if (i < xcount) {
            float4 v = *(const float4*)(x + i);
            ushort4 h4v;
            h4v.x = f2bf(v.x); h4v.y = f2bf(v.y);
            h4v.z = f2bf(v.z); h4v.w = f2bf(v.w);
            *(ushort4*)(xh + i) = h4v;
        }
    }
}

// ---------------- MFMA GEMM (fwd+bwd via blockIdx.z) ----------------
// C[M,N] = Ahi[M,256] @ (Bhi+Blo)[N,256]^T ; tile 128x128, BK=32, 4 waves.
// 2-pass MFMA (ah*bh + ah*bl), hi-only output, optional per-row scale.
__global__ __launch_bounds__(256)
void k_gemm(const u16* __restrict__ A0, const u16* __restrict__ A1p,
            const u16* __restrict__ Bhi0, const u16* __restrict__ Blo0,
            const u16* __restrict__ Bhi1, const u16* __restrict__ Blo1, int ldb,
            u16* __restrict__ C0, u16* __restrict__ C1,
            const float* __restrict__ rs0, const float* __restrict__ rs1,
            int M, int N)
{
    __shared__ char smem[24576];   // A@0  Bhi@8192  Blo@16384

    const int z = blockIdx.z;
    const u16* Ah  = z ? A1p : A0;
    const u16* Bhi = z ? Bhi1 : Bhi0;
    const u16* Blo = z ? Blo1 : Blo0;
    u16* Chi       = z ? C1 : C0;
    const float* rowscale = z ? rs1 : rs0;

    const int tid  = threadIdx.x;
    const int lane = tid & 63;
    const int wid  = tid >> 6;
    const int wm   = wid >> 1, wn = wid & 1;
    const int bm   = blockIdx.x * 128;
    const int bn   = blockIdx.y * 128;

    f32x4 acc[4][4];
#pragma unroll
    for (int i = 0; i < 4; ++i)
#pragma unroll
        for (int j = 0; j < 4; ++j) acc[i][j] = (f32x4){0.f, 0.f, 0.f, 0.f};

    const int gsw  = ((lane >> 2) & 3) ^ ((lane >> 4) & 3);
    const int gsta = ((lane & 3) ^ gsw) << 4;
    const int sl   = (lane & 3) ^ ((lane >> 2) & 3);
    const int hi4  = lane >> 4;
    const int gsel = ((hi4 ^ sl) << 4);
    const int frow = lane & 15;

    for (int k0 = 0; k0 < 256; k0 += 32) {
        if (k0) __syncthreads();

#pragma unroll
        for (int p = 0; p < 2; ++p) {
            int c   = p * 4 + wid;
            int row = c * 16 + (lane >> 2);
            size_t rb = (size_t)(bn + row) * ldb + (size_t)k0 * 2 + gsta;
            gl_lds16((const char*)Bhi + rb, smem + 8192 + c * 1024);
            gl_lds16((const char*)Blo + rb, smem + 16384 + c * 1024);
        }
#pragma unroll
        for (int p = 0; p < 2; ++p) {
            int c   = p * 4 + wid;
            int row = c * 16 + (lane >> 2);
            int grow = bm + row; if (grow >= M) grow = M - 1;
            size_t rb = (size_t)grow * 512 + (size_t)k0 * 2 + gsta;
            gl_lds16((const char*)Ah + rb, smem + c * 1024);
        }
        __syncthreads();

        bf16x8 ah[4], bh[4], bl[4];
#pragma unroll
        for (int fm = 0; fm < 4; ++fm) {
            int r = wm * 64 + fm * 16 + frow;
            ah[fm] = *(const bf16x8*)(smem + r * 64 + gsel);
        }
#pragma unroll
        for (int fn = 0; fn < 4; ++fn) {
            int r = wn * 64 + fn * 16 + frow;
            bh[fn] = *(const bf16x8*)(smem + 8192 + r * 64 + gsel);
            bl[fn] = *(const bf16x8*)(smem + 16384 + r * 64 + gsel);
        }
#pragma unroll
        for (int fm = 0; fm < 4; ++fm)
#pragma unroll
            for (int fn = 0; fn < 4; ++fn)
                acc[fm][fn] = __builtin_amdgcn_mfma_f32_16x16x32_bf16(ah[fm], bh[fn], acc[fm][fn], 0, 0, 0);
#pragma unroll
        for (int fm = 0; fm < 4; ++fm)
#pragma unroll
            for (int fn = 0; fn < 4; ++fn)
                acc[fm][fn] = __builtin_amdgcn_mfma_f32_16x16x32_bf16(ah[fm], bl[fn], acc[fm][fn], 0, 0, 0);
    }

#pragma unroll
    for (int fm = 0; fm < 4; ++fm) {
#pragma unroll
        for (int q = 0; q < 4; ++q) {
            int row = bm + wm * 64 + fm * 16 + hi4 * 4 + q;
            if (row < M) {
                float s = rowscale ? rowscale[row] : 1.0f;
#pragma unroll
                for (int fn = 0; fn < 4; ++fn) {
                    int col = bn + wn * 64 + fn * 16 + frow;
                    Chi[(size_t)row * N + col] = f2bf(acc[fm][fn][q] * s);
                }
            }
        }
    }
}

// ---------------- layer-1 aggregation: 2 nodes/wave, hi-only in/out, unroll-8 ----------------
__global__ __launch_bounds__(256)
void k_agg1(const u16* __restrict__ ghf, const u16* __restrict__ ghb,
            const int* __restrict__ off_f, const int* __restrict__ lst_f,
            const int* __restrict__ off_b, const int* __restrict__ lst_b,
            const float* __restrict__ dinv_f, const float* __restrict__ dinv_b,
            const float* __restrict__ b_f, const float* __restrict__ b_b,
            u16* __restrict__ ozf, u16* __restrict__ ozb, int n)
{
    int nb = gridDim.x >> 1;
    int stack = blockIdx.x >= nb;
    int bx = stack ? (blockIdx.x - nb) : blockIdx.x;
    const u16* gh = stack ? ghb : ghf;
    const int* off = stack ? off_b : off_f;
    const int* lst = stack ? lst_b : lst_f;
    const float* dinv = stack ? dinv_b : dinv_f;
    const float* bias = stack ? b_b : b_f;
    u16* oz = stack ? ozb : ozf;

    int wv = threadIdx.x >> 6;
    int half = (threadIdx.x >> 5) & 1;
    int l = threadIdx.x & 31;
    int v = bx * 8 + wv * 2 + half;
    if (v >= n) return;
    int f0 = l * 8;                        // 8 features, 16 B per lane

    uint4 qh = *(const uint4*)(gh + (size_t)v * 256 + f0);
    float a0 = lof(qh.x), a1 = hif(qh.x);
    float a2 = lof(qh.y), a3 = hif(qh.y);
    float a4 = lof(qh.z), a5 = hif(qh.z);
    float a6 = lof(qh.w), a7 = hif(qh.w);

    int s0 = off[v], s1 = off[v + 1];
    int j = s0;
    for (; j + 8 <= s1; j += 8) {
        uint4 m[8];
#pragma unroll
        for (int q = 0; q < 8; ++q) {
            int u = lst[j + q];
            m[q] = *(const uint4*)(gh + (size_t)u * 256 + f0);
        }
#pragma unroll
        for (int q = 0; q < 8; ++q) {
            a0 += lof(m[q].x); a1 += hif(m[q].x);
            a2 += lof(m[q].y); a3 += hif(m[q].y);
            a4 += lof(m[q].z); a5 += hif(m[q].z);
            a6 += lof(m[q].w); a7 += hif(m[q].w);
        }
    }
    for (; j + 4 <= s1; j += 4) {
        uint4 m[4];
#pragma unroll
        for (int q = 0; q < 4; ++q) {
            int u = lst[j + q];
            m[q] = *(const uint4*)(gh + (size_t)u * 256 + f0);
        }
#pragma unroll
        for (int q = 0; q < 4; ++q) {
            a0 += lof(m[q].x); a1 += hif(m[q].x);
            a2 += lof(m[q].y); a3 += hif(m[q].y);
            a4 += lof(m[q].z); a5 += hif(m[q].z);
            a6 += lof(m[q].w); a7 += hif(m[q].w);
        }
    }
    for (; j < s1; ++j) {
        int u = lst[j];
        uint4 m = *(const uint4*)(gh + (size_t)u * 256 + f0);
        a0 += lof(m.x); a1 += hif(m.x);
        a2 += lof(m.y); a3 += hif(m.y);
        a4 += lof(m.z); a5 += hif(m.z);
        a6 += lof(m.w); a7 += hif(m.w);
    }
    float sc = dinv[v];
    float4 bA = *(const float4*)(bias + f0);
    float4 bB = *(const float4*)(bias + f0 + 4);
    float o0 = fmaxf(a0 * sc + bA.x, 0.f), o1 = fmaxf(a1 * sc + bA.y, 0.f);
    float o2 = fmaxf(a2 * sc + bA.z, 0.f), o3 = fmaxf(a3 * sc + bA.w, 0.f);
    float o4 = fmaxf(a4 * sc + bB.x, 0.f), o5 = fmaxf(a5 * sc + bB.y, 0.f);
    float o6 = fmaxf(a6 * sc + bB.z, 0.f), o7 = fmaxf(a7 * sc + bB.w, 0.f);
    uint4 r;
    r.x = pk(o0, o1); r.y = pk(o2, o3); r.z = pk(o4, o5); r.w = pk(o6, o7);
    *(uint4*)(oz + (size_t)v * 256 + f0) = r;
}

// ---------------- final aggregation: dir-split lanes, hi-only Y -> f32 out ----------------
__global__ __launch_bounds__(256)
void k_agg2(const u16* __restrict__ yf, const u16* __restrict__ yb,
            const int* __restrict__ off_f, const int* __restrict__ lst_f,
            const int* __restrict__ off_b, const int* __restrict__ lst_b,
            const float* __restrict__ dinv_f, const float* __restrict__ dinv_b,
            const float* __restrict__ cvec, float* __restrict__ out, int n)
{
    int wv = threadIdx.x >> 6, lane = threadIdx.x & 63;
    int v = blockIdx.x * 4 + wv;
    if (v >= n) return;
    int dirb = lane >> 5;
    int l = lane & 31;
    int f0 = l * 4;

    const u16* y   = dirb ? yb : yf;
    const int* off = dirb ? off_b : off_f;
    const int* lst = dirb ? lst_b : lst_f;
    float dv = dirb ? dinv_b[v] : dinv_f[v];

    uint2 q = *(const uint2*)(y + (size_t)v * 128 + f0);
    float a0 = lof(q.x), a1 = hif(q.x), a2 = lof(q.y), a3 = hif(q.y);

    int s0 = off[v], s1 = off[v + 1];
    int j = s0;
    for (; j + 4 <= s1; j += 4) {
        int u0 = lst[j], u1 = lst[j + 1], u2 = lst[j + 2], u3 = lst[j + 3];
        uint2 m0 = *(const uint2*)(y + (size_t)u0 * 128 + f0);
        uint2 m1 = *(const uint2*)(y + (size_t)u1 * 128 + f0);
        uint2 m2 = *(const uint2*)(y + (size_t)u2 * 128 + f0);
        uint2 m3 = *(const uint2*)(y + (size_t)u3 * 128 + f0);
        a0 += lof(m0.x) + lof(m1.x) + lof(m2.x) + lof(m3.x);
        a1 += hif(m0.x) + hif(m1.x) + hif(m2.x) + hif(m3.x);
        a2 += lof(m0.y) + lof(m1.y) + lof(m2.y) + lof(m3.y);
        a3 += hif(m0.y) + hif(m1.y) + hif(m2.y) + hif(m3.y);
    }
    for (; j < s1; ++j) {
        int u = lst[j];
        uint2 m = *(const uint2*)(y + (size_t)u * 128 + f0);
        a0 += lof(m.x); a1 += hif(m.x);
        a2 += lof(m.y); a3 += hif(m.y);
    }
    float o0 = a0 * dv, o1 = a1 * dv, o2 = a2 * dv, o3 = a3 * dv;
    o0 += __shfl_xor(o0, 32);
    o1 += __shfl_xor(o1, 32);
    o2 += __shfl_xor(o2, 32);
    o3 += __shfl_xor(o3, 32);
    if (dirb == 0) {
        float4 c4 = *(const float4*)(cvec + f0);
        float4 o;
        o.x = o0 + c4.x; o.y = o1 + c4.y; o.z = o2 + c4.z; o.w = o3 + c4.w;
        *(float4*)(out + (size_t)v * 128 + f0) = o;
    }
}

extern "C" void kernel_launch(void* const* d_in, const int* in_sizes, int n_in,
                              void* d_out, int out_size, void* d_ws, size_t ws_size,
                              hipStream_t stream) {
    const float* x    = (const float*)d_in[0];
    const int*   ei   = (const int*)d_in[1];
    const float* Wf1  = (const float*)d_in[2];
    const float* bf1  = (const float*)d_in[3];
    const float* Wf2  = (const float*)d_in[4];
    const float* bf2  = (const float*)d_in[5];
    const float* Wb1  = (const float*)d_in[6];
    const float* bb1  = (const float*)d_in[7];
    const float* Wb2  = (const float*)d_in[8];
    const float* bb2  = (const float*)d_in[9];
    const float* Wfin = (const float*)d_in[10];
    const float* bfin = (const float*)d_in[11];
    float* out = (float*)d_out;

    const int n = in_sizes[0] / 256;   // 20000
    const int E = in_sizes[1] / 2;     // 320000
    const int* src = ei;
    const int* dst = ei + E;

    char* p = (char*)d_ws;
    auto take = [&](size_t bytes) -> void* {
        void* q = (void*)p;
        p += (bytes + 255) & ~(size_t)255;
        return q;
    };
    // activation planes (hi-only except none need lo now)
    u16* Xh    = (u16*)take((size_t)n * 256 * 2);
    u16* P1f   = (u16*)take((size_t)n * 256 * 2);
    u16* P1b   = (u16*)take((size_t)n * 256 * 2);
    u16* Zf    = (u16*)take((size_t)n * 256 * 2);
    u16* Zb    = (u16*)take((size_t)n * 256 * 2);
    u16* H2f   = (u16*)take((size_t)n * 256 * 2);
    u16* H2b   = (u16*)take((size_t)n * 256 * 2);
    u16* Yf    = (u16*)take((size_t)n * 128 * 2);
    u16* Yb    = (u16*)take((size_t)n * 128 * 2);
    // weight planes
    u16* w1f_h = (u16*)take(65536 * 2); u16* w1f_l = (u16*)take(65536 * 2);
    u16* w2f_h = (u16*)take(65536 * 2); u16* w2f_l = (u16*)take(65536 * 2);
    u16* w1b_h = (u16*)take(65536 * 2); u16* w1b_l = (u16*)take(65536 * 2);
    u16* w2b_h = (u16*)take(65536 * 2); u16* w2b_l = (u16*)take(65536 * 2);
    u16* wfin_h = (u16*)take(65536 * 2); u16* wfin_l = (u16*)take(65536 * 2);
    float* cvec = (float*)take(128 * sizeof(float));
    // CSR
    int*   deg_f  = (int*)take((size_t)n * sizeof(int));
    int*   deg_b  = (int*)take((size_t)n * sizeof(int));
    int*   off_f  = (int*)take((size_t)(n + 1) * sizeof(int));
    int*   off_b  = (int*)take((size_t)(n + 1) * sizeof(int));
    int*   cur_f  = (int*)take((size_t)n * sizeof(int));
    int*   cur_b  = (int*)take((size_t)n * sizeof(int));
    int*   lst_f  = (int*)take((size_t)E * sizeof(int));
    int*   lst_b  = (int*)take((size_t)E * sizeof(int));
    float* dinv_f = (float*)take((size_t)n * sizeof(float));
    float* dinv_b = (float*)take((size_t)n * sizeof(float));
    int*   bsum   = (int*)take(256 * sizeof(int));
    int*   bpre   = (int*)take(256 * sizeof(int));

    hipMemsetAsync(deg_f, 0, (size_t)n * sizeof(int), stream);
    hipMemsetAsync(deg_b, 0, (size_t)n * sizeof(int), stream);

    const int nblk = (n + 255) / 256;     // 79 (<=128 for k_scan2)
    const int xcount = n * 256;
    const int xblocks = (xcount + 1023) / 1024;
    int eb = (E + 255) / 256;

    k_deg<<<eb, 256, 0, stream>>>(src, dst, deg_f, deg_b, E);
    k_scan1<<<2 * nblk, 256, 0, stream>>>(deg_f, deg_b, dinv_f, dinv_b, bsum, n, nblk);
    k_scan2<<<1, 256, 0, stream>>>(bsum, bpre, nblk);
    k_scan3<<<2 * nblk, 256, 0, stream>>>(deg_f, deg_b, bpre,
        off_f, cur_f, off_b, cur_b, n, nblk, E);
    k_fill<<<eb, 256, 0, stream>>>(src, dst, cur_f, cur_b, lst_f, lst_b, E);
    k_prep<<<1408 + xblocks, 256, 0, stream>>>(Wf1, Wf2, Wb1, Wb2, Wfin,
        w1f_h, w1f_l, w2f_h, w2f_l, w1b_h, w1b_l, w2b_h, w2b_l, wfin_h, wfin_l,
        bfin, bf2, bb2, cvec, x, Xh, xcount);

    const int gx = (n + 127) / 128;       // 157
    dim3 gBig(gx, 2, 2);                  // N=256, fwd+bwd
    dim3 gFin(gx, 1, 2);                  // N=128, fwd+bwd
    int ab = (n + 3) / 4;
    int a1b = 2 * ((n + 7) / 8);

    // G1: h1 = (xh @ W1) * dinv
    k_gemm<<<gBig, 256, 0, stream>>>(Xh, Xh,
        w1f_h, w1f_l, w1b_h, w1b_l, 512,
        P1f, P1b, dinv_f, dinv_b, n, 256);
    // A1: z1 = relu(dinv * agg(h1) + b1)
    k_agg1<<<a1b, 256, 0, stream>>>(P1f, P1b,
        off_f, lst_f, off_b, lst_b, dinv_f, dinv_b, bf1, bb1, Zf, Zb, n);
    // G2: h2 = (z1 @ W2) * dinv
    k_gemm<<<gBig, 256, 0, stream>>>(Zf, Zb,
        w2f_h, w2f_l, w2b_h, w2b_l, 512,
        H2f, H2b, dinv_f, dinv_b, n, 256);
    // Gfin: y = h2 @ Wfin_half
    k_gemm<<<gFin, 256, 0, stream>>>(H2f, H2b,
        wfin_h, wfin_l, wfin_h + 256, wfin_l + 256, 1024,
        Yf, Yb, nullptr, nullptr, n, 128);
    // A2: out = dinv_f*agg_f(yf) + dinv_b*agg_b(yb) + cvec
    k_agg2<<<ab, 256, 0, stream>>>(Yf, Yb,
        off_f, lst_f, off_b, lst_b, dinv_f, dinv_b, cvec, out, n);
}

// Round 15
// 265.929 us; speedup vs baseline: 2.3821x; 1.0526x over previous
//
#include <hip/hip_runtime.h>

typedef unsigned int   u32;
typedef unsigned short u16;
typedef __attribute__((ext_vector_type(8))) short bf16x8;
typedef __attribute__((ext_vector_type(4))) float f32x4;

// ---------- bf16 helpers ----------
__device__ __forceinline__ u16 f2bf(float f) {
    u32 u = __float_as_uint(f);
    u32 r = u + 0x7fffu + ((u >> 16) & 1u);
    return (u16)(r >> 16);
}
__device__ __forceinline__ float bf2f(u16 h) {
    return __uint_as_float(((u32)h) << 16);
}
__device__ __forceinline__ float lof(u32 q) { return __uint_as_float(q << 16); }
__device__ __forceinline__ float hif(u32 q) { return __uint_as_float(q & 0xffff0000u); }
__device__ __forceinline__ u32 pk(float a, float b) {
    return (u32)f2bf(a) | ((u32)f2bf(b) << 16);
}
__device__ __forceinline__ void gl_lds16(const void* g, void* l) {
    __builtin_amdgcn_global_load_lds(
        (const __attribute__((address_space(1))) u32*)g,
        (__attribute__((address_space(3))) u32*)l, 16, 0, 0);
}

// ---------------- degree count ----------------
__global__ __launch_bounds__(256)
void k_deg(const int* __restrict__ src, const int* __restrict__ dst,
           int* __restrict__ deg_f, int* __restrict__ deg_b, int E) {
    int e = blockIdx.x * 256 + threadIdx.x;
    if (e < E) {
        atomicAdd(&deg_f[dst[e]], 1);
        atomicAdd(&deg_b[src[e]], 1);
    }
}

// ---------------- hierarchical scan, stage 1: per-block sums + dinv ----------------
__global__ __launch_bounds__(256)
void k_scan1(const int* __restrict__ deg_f, const int* __restrict__ deg_b,
             float* __restrict__ dinv_f, float* __restrict__ dinv_b,
             int* __restrict__ bsum, int n, int nblk) {
    __shared__ int red[4];
    int dir = blockIdx.x >= nblk;
    int b = dir ? blockIdx.x - nblk : blockIdx.x;
    const int* deg = dir ? deg_b : deg_f;
    float* dinv = dir ? dinv_b : dinv_f;
    int idx = b * 256 + threadIdx.x;
    int d = 0;
    if (idx < n) {
        d = deg[idx];
        dinv[idx] = rsqrtf((float)(d + 1));
    }
    int s = d;
    s += __shfl_down(s, 32);
    s += __shfl_down(s, 16);
    s += __shfl_down(s, 8);
    s += __shfl_down(s, 4);
    s += __shfl_down(s, 2);
    s += __shfl_down(s, 1);
    int wv = threadIdx.x >> 6;
    if ((threadIdx.x & 63) == 0) red[wv] = s;
    __syncthreads();
    if (threadIdx.x == 0)
        bsum[blockIdx.x] = red[0] + red[1] + red[2] + red[3];
}

// ---------------- stage 2: segmented exclusive scan of block sums ----------------
__global__ __launch_bounds__(256)
void k_scan2(const int* __restrict__ bsum, int* __restrict__ bpre, int nblk) {
    __shared__ int sm[256];
    int t = threadIdx.x;
    int seg = t >> 7;
    int i = t & 127;
    int val = (i < nblk) ? bsum[seg * nblk + i] : 0;
    sm[t] = val;
    __syncthreads();
    for (int s = 1; s < 128; s <<= 1) {
        int v = ((t & 127) >= s) ? sm[t - s] : 0;
        __syncthreads();
        sm[t] += v;
        __syncthreads();
    }
    if (i < nblk) bpre[seg * nblk + i] = sm[t] - val;
}

// ---------------- stage 3: local scan + block offset -> off/cur ----------------
__global__ __launch_bounds__(256)
void k_scan3(const int* __restrict__ deg_f, const int* __restrict__ deg_b,
             const int* __restrict__ bpre,
             int* __restrict__ off_f, int* __restrict__ cur_f,
             int* __restrict__ off_b, int* __restrict__ cur_b,
             int n, int nblk, int E) {
    __shared__ int sm[256];
    int dir = blockIdx.x >= nblk;
    int b = dir ? blockIdx.x - nblk : blockIdx.x;
    const int* deg = dir ? deg_b : deg_f;
    int* off = dir ? off_b : off_f;
    int* cur = dir ? cur_b : cur_f;
    int base = bpre[blockIdx.x];
    int idx = b * 256 + threadIdx.x;
    int d = (idx < n) ? deg[idx] : 0;
    sm[threadIdx.x] = d;
    __syncthreads();
    for (int s = 1; s < 256; s <<= 1) {
        int v = (threadIdx.x >= s) ? sm[threadIdx.x - s] : 0;
        __syncthreads();
        sm[threadIdx.x] += v;
        __syncthreads();
    }
    if (idx < n) {
        int excl = base + sm[threadIdx.x] - d;
        off[idx] = excl;
        cur[idx] = excl;
    }
    if (blockIdx.x == 0 && threadIdx.x == 0) {
        off_f[n] = E;
        off_b[n] = E;
    }
}

// ---------------- CSR fill ----------------
__global__ __launch_bounds__(256)
void k_fill(const int* __restrict__ src, const int* __restrict__ dst,
            int* __restrict__ cur_f, int* __restrict__ cur_b,
            int* __restrict__ lst_f, int* __restrict__ lst_b, int E) {
    int e = blockIdx.x * 256 + threadIdx.x;
    if (e < E) {
        int s = src[e], d = dst[e];
        int pf = atomicAdd(&cur_f[d], 1);
        lst_f[pf] = s;
        int pb = atomicAdd(&cur_b[s], 1);
        lst_b[pb] = d;
    }
}

// ---------------- fused prep ----------------
// blocks [0,512):    W1 transpose+split (Wf1, Wb1; 256 blocks each)
// blocks [512,640):  cvec column j = b-512
// blocks [640,1152): Wc = W2 @ Wfin_half (2 dirs x 256 rows), transposed hi/lo out
// blocks [1152,...): x -> bf16 hi plane, 1024 elems/block
__global__ __launch_bounds__(256)
void k_prep(const float* __restrict__ Wf1, const float* __restrict__ Wb1,
            const float* __restrict__ Wf2, const float* __restrict__ Wb2,
            const float* __restrict__ Wfin,
            u16* __restrict__ w1f_h, u16* __restrict__ w1f_l,
            u16* __restrict__ w1b_h, u16* __restrict__ w1b_l,
            u16* __restrict__ wcf_h, u16* __restrict__ wcf_l,
            u16* __restrict__ wcb_h, u16* __restrict__ wcb_l,
            const float* __restrict__ bfin, const float* __restrict__ bf2,
            const float* __restrict__ bb2, float* __restrict__ cvec,
            const float* __restrict__ x, u16* __restrict__ xh, int xcount)
{
    __shared__ float red[256];
    int b = blockIdx.x;
    int t = threadIdx.x;
    if (b < 512) {
        int which = b >> 8;
        int sub = ((b & 255) << 8) | t;          // 0..65535
        const float* W = which ? Wb1 : Wf1;
        u16* H = which ? w1b_h : w1f_h;
        u16* L = which ? w1b_l : w1f_l;
        int ni = sub >> 8;
        int ki = sub & 255;
        float v = W[(size_t)ki * 256 + ni];
        u16 hh = f2bf(v);
        H[sub] = hh;
        L[sub] = f2bf(v - bf2f(hh));
    } else if (b < 640) {
        int j = b - 512;   // 0..127
        float s = bf2[t] * Wfin[(size_t)t * 128 + j]
                + bb2[t] * Wfin[(size_t)(t + 256) * 128 + j];
        red[t] = s;
        __syncthreads();
        for (int st = 128; st > 0; st >>= 1) {
            if (t < st) red[t] += red[t + st];
            __syncthreads();
        }
        if (t == 0) cvec[j] = red[0] + bfin[j];
    } else if (b < 1152) {
        int idx = b - 640;
        int dir = idx >> 8;          // 0: fwd, 1: bwd
        int i = idx & 255;           // row of W2
        const float* W2 = dir ? Wb2 : Wf2;
        u16* H = dir ? wcb_h : wcf_h;
        u16* L = dir ? wcb_l : wcf_l;
        if (t < 128) {
            int j = t;
            float s = 0.f;
            const float* wf = Wfin + (size_t)(dir * 256) * 128 + j;
            const float* w2r = W2 + (size_t)i * 256;
            for (int k = 0; k < 256; ++k)
                s += w2r[k] * wf[(size_t)k * 128];
            u16 hh = f2bf(s);
            H[(size_t)j * 256 + i] = hh;
            L[(size_t)j * 256 + i] = f2bf(s - bf2f(hh));
        }
    } else {
        int i = (b - 1152) * 1024 + t * 4;
        if (i < xcount) {
            float4 v = *(const float4*)(x + i);
            ushort4 h4v;
            h4v.x = f2bf(v.x); h4v.y = f2bf(v.y);
            h4v.z = f2bf(v.z); h4v.w = f2bf(v.w);
            *(ushort4*)(xh + i) = h4v;
        }
    }
}

// ---------------- MFMA GEMM (fwd+bwd via blockIdx.z) ----------------
// C[M,N] = Ahi[M,256] @ (Bhi+Blo)[N,256]^T ; tile 128x128, BK=32, 4 waves.
// 2-pass MFMA (ah*bh + ah*bl), hi-only output, optional per-row scale.
__global__ __launch_bounds__(256)
void k_gemm(const u16* __restrict__ A0, const u16* __restrict__ A1p,
            const u16* __restrict__ Bhi0, const u16* __restrict__ Blo0,
            const u16* __restrict__ Bhi1, const u16* __restrict__ Blo1, int ldb,
            u16* __restrict__ C0, u16* __restrict__ C1,
            const float* __restrict__ rs0, const float* __restrict__ rs1,
            int M, int N)
{
    __shared__ char smem[24576];   // A@0  Bhi@8192  Blo@16384

    const int z = blockIdx.z;
    const u16* Ah  = z ? A1p : A0;
    const u16* Bhi = z ? Bhi1 : Bhi0;
    const u16* Blo = z ? Blo1 : Blo0;
    u16* Chi       = z ? C1 : C0;
    const float* rowscale = z ? rs1 : rs0;

    const int tid  = threadIdx.x;
    const int lane = tid & 63;
    const int wid  = tid >> 6;
    const int wm   = wid >> 1, wn = wid & 1;
    const int bm   = blockIdx.x * 128;
    const int bn   = blockIdx.y * 128;

    f32x4 acc[4][4];
#pragma unroll
    for (int i = 0; i < 4; ++i)
#pragma unroll
        for (int j = 0; j < 4; ++j) acc[i][j] = (f32x4){0.f, 0.f, 0.f, 0.f};

    const int gsw  = ((lane >> 2) & 3) ^ ((lane >> 4) & 3);
    const int gsta = ((lane & 3) ^ gsw) << 4;
    const int sl   = (lane & 3) ^ ((lane >> 2) & 3);
    const int hi4  = lane >> 4;
    const int gsel = ((hi4 ^ sl) << 4);
    const int frow = lane & 15;

    for (int k0 = 0; k0 < 256; k0 += 32) {
        if (k0) __syncthreads();

#pragma unroll
        for (int p = 0; p < 2; ++p) {
            int c   = p * 4 + wid;
            int row = c * 16 + (lane >> 2);
            size_t rb = (size_t)(bn + row) * ldb + (size_t)k0 * 2 + gsta;
            gl_lds16((const char*)Bhi + rb, smem + 8192 + c * 1024);
            gl_lds16((const char*)Blo + rb, smem + 16384 + c * 1024);
        }
#pragma unroll
        for (int p = 0; p < 2; ++p) {
            int c   = p * 4 + wid;
            int row = c * 16 + (lane >> 2);
            int grow = bm + row; if (grow >= M) grow = M - 1;
            size_t rb = (size_t)grow * 512 + (size_t)k0 * 2 + gsta;
            gl_lds16((const char*)Ah + rb, smem + c * 1024);
        }
        __syncthreads();

        bf16x8 ah[4], bh[4], bl[4];
#pragma unroll
        for (int fm = 0; fm < 4; ++fm) {
            int r = wm * 64 + fm * 16 + frow;
            ah[fm] = *(const bf16x8*)(smem + r * 64 + gsel);
        }
#pragma unroll
        for (int fn = 0; fn < 4; ++fn) {
            int r = wn * 64 + fn * 16 + frow;
            bh[fn] = *(const bf16x8*)(smem + 8192 + r * 64 + gsel);
            bl[fn] = *(const bf16x8*)(smem + 16384 + r * 64 + gsel);
        }
#pragma unroll
        for (int fm = 0; fm < 4; ++fm)
#pragma unroll
            for (int fn = 0; fn < 4; ++fn)
                acc[fm][fn] = __builtin_amdgcn_mfma_f32_16x16x32_bf16(ah[fm], bh[fn], acc[fm][fn], 0, 0, 0);
#pragma unroll
        for (int fm = 0; fm < 4; ++fm)
#pragma unroll
            for (int fn = 0; fn < 4; ++fn)
                acc[fm][fn] = __builtin_amdgcn_mfma_f32_16x16x32_bf16(ah[fm], bl[fn], acc[fm][fn], 0, 0, 0);
    }

#pragma unroll
    for (int fm = 0; fm < 4; ++fm) {
#pragma unroll
        for (int q = 0; q < 4; ++q) {
            int row = bm + wm * 64 + fm * 16 + hi4 * 4 + q;
            if (row < M) {
                float s = rowscale ? rowscale[row] : 1.0f;
#pragma unroll
                for (int fn = 0; fn < 4; ++fn) {
                    int col = bn + wn * 64 + fn * 16 + frow;
                    Chi[(size_t)row * N + col] = f2bf(acc[fm][fn][q] * s);
                }
            }
        }
    }
}

// ---------------- layer-1 aggregation: 2 nodes/wave, hi-only in/out, unroll-8 ----------------
__global__ __launch_bounds__(256)
void k_agg1(const u16* __restrict__ ghf, const u16* __restrict__ ghb,
            const int* __restrict__ off_f, const int* __restrict__ lst_f,
            const int* __restrict__ off_b, const int* __restrict__ lst_b,
            const float* __restrict__ dinv_f, const float* __restrict__ dinv_b,
            const float* __restrict__ b_f, const float* __restrict__ b_b,
            u16* __restrict__ ozf, u16* __restrict__ ozb, int n)
{
    int nb = gridDim.x >> 1;
    int stack = blockIdx.x >= nb;
    int bx = stack ? (blockIdx.x - nb) : blockIdx.x;
    const u16* gh = stack ? ghb : ghf;
    const int* off = stack ? off_b : off_f;
    const int* lst = stack ? lst_b : lst_f;
    const float* dinv = stack ? dinv_b : dinv_f;
    const float* bias = stack ? b_b : b_f;
    u16* oz = stack ? ozb : ozf;

    int wv = threadIdx.x >> 6;
    int half = (threadIdx.x >> 5) & 1;
    int l = threadIdx.x & 31;
    int v = bx * 8 + wv * 2 + half;
    if (v >= n) return;
    int f0 = l * 8;                        // 8 features, 16 B per lane

    uint4 qh = *(const uint4*)(gh + (size_t)v * 256 + f0);
    float a0 = lof(qh.x), a1 = hif(qh.x);
    float a2 = lof(qh.y), a3 = hif(qh.y);
    float a4 = lof(qh.z), a5 = hif(qh.z);
    float a6 = lof(qh.w), a7 = hif(qh.w);

    int s0 = off[v], s1 = off[v + 1];
    int j = s0;
    for (; j + 8 <= s1; j += 8) {
        uint4 m[8];
#pragma unroll
        for (int q = 0; q < 8; ++q) {
            int u = lst[j + q];
            m[q] = *(const uint4*)(gh + (size_t)u * 256 + f0);
        }
#pragma unroll
        for (int q = 0; q < 8; ++q) {
            a0 += lof(m[q].x); a1 += hif(m[q].x);
            a2 += lof(m[q].y); a3 += hif(m[q].y);
            a4 += lof(m[q].z); a5 += hif(m[q].z);
            a6 += lof(m[q].w); a7 += hif(m[q].w);
        }
    }
    for (; j + 4 <= s1; j += 4) {
        uint4 m[4];
#pragma unroll
        for (int q = 0; q < 4; ++q) {
            int u = lst[j + q];
            m[q] = *(const uint4*)(gh + (size_t)u * 256 + f0);
        }
#pragma unroll
        for (int q = 0; q < 4; ++q) {
            a0 += lof(m[q].x); a1 += hif(m[q].x);
            a2 += lof(m[q].y); a3 += hif(m[q].y);
            a4 += lof(m[q].z); a5 += hif(m[q].z);
            a6 += lof(m[q].w); a7 += hif(m[q].w);
        }
    }
    for (; j < s1; ++j) {
        int u = lst[j];
        uint4 m = *(const uint4*)(gh + (size_t)u * 256 + f0);
        a0 += lof(m.x); a1 += hif(m.x);
        a2 += lof(m.y); a3 += hif(m.y);
        a4 += lof(m.z); a5 += hif(m.z);
        a6 += lof(m.w); a7 += hif(m.w);
    }
    float sc = dinv[v];
    float4 bA = *(const float4*)(bias + f0);
    float4 bB = *(const float4*)(bias + f0 + 4);
    float o0 = fmaxf(a0 * sc + bA.x, 0.f), o1 = fmaxf(a1 * sc + bA.y, 0.f);
    float o2 = fmaxf(a2 * sc + bA.z, 0.f), o3 = fmaxf(a3 * sc + bA.w, 0.f);
    float o4 = fmaxf(a4 * sc + bB.x, 0.f), o5 = fmaxf(a5 * sc + bB.y, 0.f);
    float o6 = fmaxf(a6 * sc + bB.z, 0.f), o7 = fmaxf(a7 * sc + bB.w, 0.f);
    uint4 r;
    r.x = pk(o0, o1); r.y = pk(o2, o3); r.z = pk(o4, o5); r.w = pk(o6, o7);
    *(uint4*)(oz + (size_t)v * 256 + f0) = r;
}

// ---------------- final aggregation: dir-split lanes, hi-only Y -> f32 out ----------------
__global__ __launch_bounds__(256)
void k_agg2(const u16* __restrict__ yf, const u16* __restrict__ yb,
            const int* __restrict__ off_f, const int* __restrict__ lst_f,
            const int* __restrict__ off_b, const int* __restrict__ lst_b,
            const float* __restrict__ dinv_f, const float* __restrict__ dinv_b,
            const float* __restrict__ cvec, float* __restrict__ out, int n)
{
    int wv = threadIdx.x >> 6, lane = threadIdx.x & 63;
    int v = blockIdx.x * 4 + wv;
    if (v >= n) return;
    int dirb = lane >> 5;
    int l = lane & 31;
    int f0 = l * 4;

    const u16* y   = dirb ? yb : yf;
    const int* off = dirb ? off_b : off_f;
    const int* lst = dirb ? lst_b : lst_f;
    float dv = dirb ? dinv_b[v] : dinv_f[v];

    uint2 q = *(const uint2*)(y + (size_t)v * 128 + f0);
    float a0 = lof(q.x), a1 = hif(q.x), a2 = lof(q.y), a3 = hif(q.y);

    int s0 = off[v], s1 = off[v + 1];
    int j = s0;
    for (; j + 4 <= s1; j += 4) {
        int u0 = lst[j], u1 = lst[j + 1], u2 = lst[j + 2], u3 = lst[j + 3];
        uint2 m0 = *(const uint2*)(y + (size_t)u0 * 128 + f0);
        uint2 m1 = *(const uint2*)(y + (size_t)u1 * 128 + f0);
        uint2 m2 = *(const uint2*)(y + (size_t)u2 * 128 + f0);
        uint2 m3 = *(const uint2*)(y + (size_t)u3 * 128 + f0);
        a0 += lof(m0.x) + lof(m1.x) + lof(m2.x) + lof(m3.x);
        a1 += hif(m0.x) + hif(m1.x) + hif(m2.x) + hif(m3.x);
        a2 += lof(m0.y) + lof(m1.y) + lof(m2.y) + lof(m3.y);
        a3 += hif(m0.y) + hif(m1.y) + hif(m2.y) + hif(m3.y);
    }
    for (; j < s1; ++j) {
        int u = lst[j];
        uint2 m = *(const uint2*)(y + (size_t)u * 128 + f0);
        a0 += lof(m.x); a1 += hif(m.x);
        a2 += lof(m.y); a3 += hif(m.y);
    }
    float o0 = a0 * dv, o1 = a1 * dv, o2 = a2 * dv, o3 = a3 * dv;
    o0 += __shfl_xor(o0, 32);
    o1 += __shfl_xor(o1, 32);
    o2 += __shfl_xor(o2, 32);
    o3 += __shfl_xor(o3, 32);
    if (dirb == 0) {
        float4 c4 = *(const float4*)(cvec + f0);
        float4 o;
        o.x = o0 + c4.x; o.y = o1 + c4.y; o.z = o2 + c4.z; o.w = o3 + c4.w;
        *(float4*)(out + (size_t)v * 128 + f0) = o;
    }
}

extern "C" void kernel_launch(void* const* d_in, const int* in_sizes, int n_in,
                              void* d_out, int out_size, void* d_ws, size_t ws_size,
                              hipStream_t stream) {
    const float* x    = (const float*)d_in[0];
    const int*   ei   = (const int*)d_in[1];
    const float* Wf1  = (const float*)d_in[2];
    const float* bf1  = (const float*)d_in[3];
    const float* Wf2  = (const float*)d_in[4];
    const float* bf2  = (const float*)d_in[5];
    const float* Wb1  = (const float*)d_in[6];
    const float* bb1  = (const float*)d_in[7];
    const float* Wb2  = (const float*)d_in[8];
    const float* bb2  = (const float*)d_in[9];
    const float* Wfin = (const float*)d_in[10];
    const float* bfin = (const float*)d_in[11];
    float* out = (float*)d_out;

    const int n = in_sizes[0] / 256;   // 20000
    const int E = in_sizes[1] / 2;     // 320000
    const int* src = ei;
    const int* dst = ei + E;

    char* p = (char*)d_ws;
    auto take = [&](size_t bytes) -> void* {
        void* q = (void*)p;
        p += (bytes + 255) & ~(size_t)255;
        return q;
    };
    // activation planes (hi-only)
    u16* Xh    = (u16*)take((size_t)n * 256 * 2);
    u16* P1f   = (u16*)take((size_t)n * 256 * 2);
    u16* P1b   = (u16*)take((size_t)n * 256 * 2);
    u16* Zf    = (u16*)take((size_t)n * 256 * 2);
    u16* Zb    = (u16*)take((size_t)n * 256 * 2);
    u16* Yf    = (u16*)take((size_t)n * 128 * 2);
    u16* Yb    = (u16*)take((size_t)n * 128 * 2);
    // weight planes
    u16* w1f_h = (u16*)take(65536 * 2); u16* w1f_l = (u16*)take(65536 * 2);
    u16* w1b_h = (u16*)take(65536 * 2); u16* w1b_l = (u16*)take(65536 * 2);
    u16* wcf_h = (u16*)take(32768 * 2); u16* wcf_l = (u16*)take(32768 * 2);
    u16* wcb_h = (u16*)take(32768 * 2); u16* wcb_l = (u16*)take(32768 * 2);
    float* cvec = (float*)take(128 * sizeof(float));
    // CSR
    int*   deg_f  = (int*)take((size_t)n * sizeof(int));
    int*   deg_b  = (int*)take((size_t)n * sizeof(int));
    int*   off_f  = (int*)take((size_t)(n + 1) * sizeof(int));
    int*   off_b  = (int*)take((size_t)(n + 1) * sizeof(int));
    int*   cur_f  = (int*)take((size_t)n * sizeof(int));
    int*   cur_b  = (int*)take((size_t)n * sizeof(int));
    int*   lst_f  = (int*)take((size_t)E * sizeof(int));
    int*   lst_b  = (int*)take((size_t)E * sizeof(int));
    float* dinv_f = (float*)take((size_t)n * sizeof(float));
    float* dinv_b = (float*)take((size_t)n * sizeof(float));
    int*   bsum   = (int*)take(256 * sizeof(int));
    int*   bpre   = (int*)take(256 * sizeof(int));

    hipMemsetAsync(deg_f, 0, (size_t)n * sizeof(int), stream);
    hipMemsetAsync(deg_b, 0, (size_t)n * sizeof(int), stream);

    const int nblk = (n + 255) / 256;     // 79 (<=128 for k_scan2)
    const int xcount = n * 256;
    const int xblocks = (xcount + 1023) / 1024;
    int eb = (E + 255) / 256;

    k_deg<<<eb, 256, 0, stream>>>(src, dst, deg_f, deg_b, E);
    k_scan1<<<2 * nblk, 256, 0, stream>>>(deg_f, deg_b, dinv_f, dinv_b, bsum, n, nblk);
    k_scan2<<<1, 256, 0, stream>>>(bsum, bpre, nblk);
    k_scan3<<<2 * nblk, 256, 0, stream>>>(deg_f, deg_b, bpre,
        off_f, cur_f, off_b, cur_b, n, nblk, E);
    k_fill<<<eb, 256, 0, stream>>>(src, dst, cur_f, cur_b, lst_f, lst_b, E);
    k_prep<<<1152 + xblocks, 256, 0, stream>>>(Wf1, Wb1, Wf2, Wb2, Wfin,
        w1f_h, w1f_l, w1b_h, w1b_l, wcf_h, wcf_l, wcb_h, wcb_l,
        bfin, bf2, bb2, cvec, x, Xh, xcount);

    const int gx = (n + 127) / 128;       // 157
    dim3 gBig(gx, 2, 2);                  // N=256, fwd+bwd
    dim3 gFin(gx, 1, 2);                  // N=128, fwd+bwd
    int ab = (n + 3) / 4;
    int a1b = 2 * ((n + 7) / 8);

    // G1: h1 = (xh @ W1) * dinv
    k_gemm<<<gBig, 256, 0, stream>>>(Xh, Xh,
        w1f_h, w1f_l, w1b_h, w1b_l, 512,
        P1f, P1b, dinv_f, dinv_b, n, 256);
    // A1: z1 = relu(dinv * agg(h1) + b1)
    k_agg1<<<a1b, 256, 0, stream>>>(P1f, P1b,
        off_f, lst_f, off_b, lst_b, dinv_f, dinv_b, bf1, bb1, Zf, Zb, n);
    // Gcomb: y = dinv * (z1 @ Wc)   where Wc = W2 @ Wfin_half (folded G2+Gfin)
    k_gemm<<<gFin, 256, 0, stream>>>(Zf, Zb,
        wcf_h, wcf_l, wcb_h, wcb_l, 512,
        Yf, Yb, dinv_f, dinv_b, n, 128);
    // A2: out = dinv_f*agg_f(yf) + dinv_b*agg_b(yb) + cvec
    k_agg2<<<ab, 256, 0, stream>>>(Yf, Yb,
        off_f, lst_f, off_b, lst_b, dinv_f, dinv_b, cvec, out, n);
}